// Round 16
// baseline (44521.997 us; speedup 1.0000x reference)
//
#include <hip/hip_runtime.h>
#include <math.h>

// NCA: B=8, H=W=256, C=16, 16 steps. fp32.
// R15 post-mortem: dbuf w0s + sparse conv -> 1.15ms step, VALU 60%, pipes
// co-critical. 256/768 ds_reads are 8x re-reads of the jc-INVARIANT perc
// slice.
// R16: hoist perc slice to pv[4][8] float4 regs ONCE (32 reads, was 256).
// ~220 live regs -> NO __launch_bounds__ (R6: allocator grants 256; R3's
// spill was the 128 default cap). Occupancy stays LDS-capped at 2 blocks.
// All pv indices literal (k4 fully unrolled). Spill signature to watch:
// VGPR<=128 or WRITE_SIZE x10.

#define HW 256
#define NPIX (8*HW*HW)   // 524288
#define PST 140          // perc row stride (floats)

__device__ __forceinline__ float4 f4max(float4 a, float4 b) {
    return make_float4(fmaxf(a.x,b.x), fmaxf(a.y,b.y), fmaxf(a.z,b.z), fmaxf(a.w,b.w));
}

// Precompute sobel bank (6 filters, 7x7, normalized).
__global__ void init_kernel(const float* __restrict__ W0,
                            float* __restrict__ filt) {
    int t = blockIdx.x * blockDim.x + threadIdx.x;
    if (t < 6) {
        int f = t;
        int size = 3 + 2*(f >> 1);
        int p0 = (7 - size) >> 1;
        int isY = f & 1;
        float vals[49];
        float norm = 0.f;
        for (int a = 0; a < 7; a++) {
            for (int b = 0; b < 7; b++) {
                float v = 0.f;
                if (a >= p0 && a < p0+size && b >= p0 && b < p0+size) {
                    float fy = (float)(a - 3), fx = (float)(b - 3);
                    float den = fx*fx + fy*fy;
                    if (den == 0.f) den = 1.f;
                    v = (isY ? fy : fx) / den;
                }
                vals[a*7+b] = v;
                norm += fabsf(v);
            }
        }
        float inv = 1.f / norm;
        for (int i = 0; i < 49; i++) filt[f*49 + i] = vals[i] * inv;
    }
}

// One 8x8 pixel tile per block, 256 threads.
__global__ void step_main(const float* __restrict__ x,
                          float* __restrict__ xmid,
                          float* __restrict__ alpha_out,
                          float* __restrict__ prelife_out,
                          const float* __restrict__ filt_g,
                          const float* __restrict__ W0,
                          const float* __restrict__ b0,
                          const float* __restrict__ W1,
                          const float* __restrict__ stoch_s) {
    // carve: phase1 xs [0,3920) + filt [3920,4214)
    //        phase2 w0sA [0,4608) | w0sB [4608,9216)
    //        perc [9216,18176)   -> 72704 B, 2 blocks/CU
    __shared__ float smem[18176];
    float* xs     = smem;          // 14*14*20 = 3920 (phase 1 only)
    float* filt_s = smem + 3920;   // 294 (phase 1 only)
    float* w0sA   = smem;          // 128x36 (phase 2)
    float* w0sB   = smem + 4608;   // 128x36 (phase 2)
    float* perc   = smem + 9216;   // 64 x 140

    const int t   = threadIdx.x;
    const int b   = blockIdx.z;
    const int ty0 = blockIdx.y * 8;
    const int tx0 = blockIdx.x * 8;

    // T14 prologue: issue chunk-0 W0 loads NOW; they land during phase 1.
    const float* pW   = W0 + ((t >> 3) << 8) + ((t & 7) << 2);
    const int   wbase = (t >> 3) * 144 + ((t & 7) << 2);
    float4 st0 = *(const float4*)(pW);
    float4 st1 = *(const float4*)(pW +  8192);
    float4 st2 = *(const float4*)(pW + 16384);
    float4 st3 = *(const float4*)(pW + 24576);

    for (int i = t; i < 294; i += 256) filt_s[i] = filt_g[i];

    // stage x tile + halo (zero pad = conv's zero padding)
    for (int v = t; v < 784; v += 256) {          // 14*14*4 float4s
        int c4  = v & 3;
        int cell = v >> 2;
        int ly = cell / 14;
        int lx = cell - ly*14;
        int gy = ty0 + ly - 3, gx = tx0 + lx - 3;
        float4 val = make_float4(0.f,0.f,0.f,0.f);
        if ((unsigned)gy < 256u && (unsigned)gx < 256u)
            val = *(const float4*)&x[((((b<<8) + gy)<<8) + gx)*16 + (c4<<2)];
        *(float4*)&xs[cell*20 + (c4<<2)] = val;
    }
    __syncthreads();

    {   // ---- phase 1: sparse conv + pools -> perc ----
        const int p  = t & 63;
        const int q  = t >> 6;
        const int py = p >> 3, px1 = p & 7;
        const int gy = ty0 + py, gx = tx0 + px1;
        const int q4 = q << 2;

        float4 y4[6];
        #pragma unroll
        for (int f = 0; f < 6; f++) y4[f] = make_float4(0.f,0.f,0.f,0.f);

        #pragma unroll
        for (int a = 0; a < 7; a++) {
            #pragma unroll
            for (int bb = 0; bb < 7; bb++) {
                float4 xv = *(const float4*)&xs[((py+a)*14 + (px1+bb))*20 + q4];
                {   // f=4,5: full 7x7
                    float w4 = filt_s[4*49 + a*7 + bb];
                    float w5 = filt_s[5*49 + a*7 + bb];
                    y4[4].x = fmaf(w4, xv.x, y4[4].x); y4[4].y = fmaf(w4, xv.y, y4[4].y);
                    y4[4].z = fmaf(w4, xv.z, y4[4].z); y4[4].w = fmaf(w4, xv.w, y4[4].w);
                    y4[5].x = fmaf(w5, xv.x, y4[5].x); y4[5].y = fmaf(w5, xv.y, y4[5].y);
                    y4[5].z = fmaf(w5, xv.z, y4[5].z); y4[5].w = fmaf(w5, xv.w, y4[5].w);
                }
                if (a >= 1 && a <= 5 && bb >= 1 && bb <= 5) {   // f=2,3: 5x5
                    float w2 = filt_s[2*49 + a*7 + bb];
                    float w3 = filt_s[3*49 + a*7 + bb];
                    y4[2].x = fmaf(w2, xv.x, y4[2].x); y4[2].y = fmaf(w2, xv.y, y4[2].y);
                    y4[2].z = fmaf(w2, xv.z, y4[2].z); y4[2].w = fmaf(w2, xv.w, y4[2].w);
                    y4[3].x = fmaf(w3, xv.x, y4[3].x); y4[3].y = fmaf(w3, xv.y, y4[3].y);
                    y4[3].z = fmaf(w3, xv.z, y4[3].z); y4[3].w = fmaf(w3, xv.w, y4[3].w);
                }
                if (a >= 2 && a <= 4 && bb >= 2 && bb <= 4) {   // f=0,1: 3x3
                    float w0 = filt_s[0*49 + a*7 + bb];
                    float w1 = filt_s[1*49 + a*7 + bb];
                    y4[0].x = fmaf(w0, xv.x, y4[0].x); y4[0].y = fmaf(w0, xv.y, y4[0].y);
                    y4[0].z = fmaf(w0, xv.z, y4[0].z); y4[0].w = fmaf(w0, xv.w, y4[0].w);
                    y4[1].x = fmaf(w1, xv.x, y4[1].x); y4[1].y = fmaf(w1, xv.y, y4[1].y);
                    y4[1].z = fmaf(w1, xv.z, y4[1].z); y4[1].w = fmaf(w1, xv.w, y4[1].w);
                }
            }
        }
        float4 m5 = make_float4(-INFINITY,-INFINITY,-INFINITY,-INFINITY);
        #pragma unroll
        for (int dy = -2; dy <= 2; dy++) {
            #pragma unroll
            for (int dx2 = -2; dx2 <= 2; dx2++) {
                if ((unsigned)(gy+dy) < 256u && (unsigned)(gx+dx2) < 256u)
                    m5 = f4max(m5, *(const float4*)&xs[((py+3+dy)*14 + (px1+3+dx2))*20 + q4]);
            }
        }
        // perc channel c stored at (c>>5)*36 + (c&31)
        float4 xc = *(const float4*)&xs[((py+3)*14 + (px1+3))*20 + q4];
        *(float4*)&perc[p*PST + q4] = xc;
        const int offY[6] = {16, 36, 52, 72, 88, 108};
        #pragma unroll
        for (int f = 0; f < 6; f++)
            *(float4*)&perc[p*PST + offY[f] + q4] = y4[f];
        *(float4*)&perc[p*PST + 124 + q4] = m5;

        if (q == 0) {
            float pre = -INFINITY;
            #pragma unroll
            for (int dy = -1; dy <= 1; dy++) {
                #pragma unroll
                for (int dx2 = -1; dx2 <= 1; dx2++) {
                    if ((unsigned)(gy+dy) < 256u && (unsigned)(gx+dx2) < 256u)
                        pre = fmaxf(pre, xs[((py+3+dy)*14 + (px1+3+dx2))*20 + 3]);
                }
            }
            prelife_out[(b << 16) + (gy << 8) + gx] = (pre > 0.1f) ? 1.f : 0.f;
        }
    }
    __syncthreads();   // xs reads done; perc published. xs region -> w0sA.

    // ---- phase 2: MLP, double-buffered w0s, perc hoisted to registers ----
    const int kq   = t & 3;
    const int jg   = (t >> 2) & 3;
    const int quad = t >> 4;        // owns 4 consecutive px {4quad..4quad+3}
    const int jg8  = jg << 3;
    const int p0px = quad << 2;

    const float* pp0 = &perc[(p0px    ) * PST + kq*36];
    const float* pp1 = &perc[(p0px + 1) * PST + kq*36];
    const float* pp2 = &perc[(p0px + 2) * PST + kq*36];
    const float* pp3 = &perc[(p0px + 3) * PST + kq*36];

    // jc-invariant perc slice -> registers (32 b128, once; literal indices)
    float4 pv0[8], pv1[8], pv2[8], pv3[8];
    #pragma unroll
    for (int r = 0; r < 8; r++) {
        pv0[r] = *(const float4*)&pp0[r << 2];
        pv1[r] = *(const float4*)&pp1[r << 2];
        pv2[r] = *(const float4*)&pp2[r << 2];
        pv3[r] = *(const float4*)&pp3[r << 2];
    }

    float dx[4][4];
    #pragma unroll
    for (int i = 0; i < 4; i++)
        #pragma unroll
        for (int c = 0; c < 4; c++) dx[i][c] = 0.f;

    // prologue: write chunk 0 -> A; issue chunk-1 loads
    *(float4*)&w0sA[wbase      ] = st0;
    *(float4*)&w0sA[wbase +  36] = st1;
    *(float4*)&w0sA[wbase +  72] = st2;
    *(float4*)&w0sA[wbase + 108] = st3;
    st0 = *(const float4*)(pW + 32);
    st1 = *(const float4*)(pW + 32 +  8192);
    st2 = *(const float4*)(pW + 32 + 16384);
    st3 = *(const float4*)(pW + 32 + 24576);
    __syncthreads();   // A visible

    #pragma unroll 1
    for (int jc = 0; jc < 8; jc++) {
        const float* wrd = (jc & 1) ? w0sB : w0sA;   // chunk jc
        float*       wwr = (jc & 1) ? w0sA : w0sB;   // chunk jc+1

        float h[4][8];
        #pragma unroll
        for (int i = 0; i < 4; i++)
            #pragma unroll
            for (int jj = 0; jj < 8; jj++) h[i][jj] = 0.f;

        #pragma unroll
        for (int k4 = 0; k4 < 32; k4 += 4) {
            float4 pA0 = pv0[k4 >> 2];
            float4 pA1 = pv1[k4 >> 2];
            float4 pA2 = pv2[k4 >> 2];
            float4 pA3 = pv3[k4 >> 2];
            #pragma unroll
            for (int kk = 0; kk < 4; kk++) {
                float a0 = kk==0?pA0.x : kk==1?pA0.y : kk==2?pA0.z : pA0.w;
                float a1 = kk==0?pA1.x : kk==1?pA1.y : kk==2?pA1.z : pA1.w;
                float a2 = kk==0?pA2.x : kk==1?pA2.y : kk==2?pA2.z : pA2.w;
                float a3 = kk==0?pA3.x : kk==1?pA3.y : kk==2?pA3.z : pA3.w;
                const float* wr = &wrd[((k4 + kk)*4 + kq)*36 + jg8];
                float4 wA = *(const float4*)wr;
                float4 wB = *(const float4*)(wr + 4);
                #pragma unroll
                for (int i = 0; i < 4; i++) {
                    float ai = i==0?a0 : i==1?a1 : i==2?a2 : a3;
                    h[i][0] = fmaf(ai, wA.x, h[i][0]);
                    h[i][1] = fmaf(ai, wA.y, h[i][1]);
                    h[i][2] = fmaf(ai, wA.z, h[i][2]);
                    h[i][3] = fmaf(ai, wA.w, h[i][3]);
                    h[i][4] = fmaf(ai, wB.x, h[i][4]);
                    h[i][5] = fmaf(ai, wB.y, h[i][5]);
                    h[i][6] = fmaf(ai, wB.z, h[i][6]);
                    h[i][7] = fmaf(ai, wB.w, h[i][7]);
                }
            }
        }
        // reduce h over the 4 kq lanes (bits 0-1)
        #pragma unroll
        for (int i = 0; i < 4; i++)
            #pragma unroll
            for (int jj = 0; jj < 8; jj++) {
                h[i][jj] += __shfl_xor(h[i][jj], 1);
                h[i][jj] += __shfl_xor(h[i][jj], 2);
            }
        // bias + relu
        const int jbase = (jc << 5) + jg8;
        float4 bA = *(const float4*)&b0[jbase];
        float4 bB = *(const float4*)&b0[jbase + 4];
        #pragma unroll
        for (int i = 0; i < 4; i++) {
            h[i][0] = fmaxf(h[i][0] + bA.x, 0.f);
            h[i][1] = fmaxf(h[i][1] + bA.y, 0.f);
            h[i][2] = fmaxf(h[i][2] + bA.z, 0.f);
            h[i][3] = fmaxf(h[i][3] + bA.w, 0.f);
            h[i][4] = fmaxf(h[i][4] + bB.x, 0.f);
            h[i][5] = fmaxf(h[i][5] + bB.y, 0.f);
            h[i][6] = fmaxf(h[i][6] + bB.z, 0.f);
            h[i][7] = fmaxf(h[i][7] + bB.w, 0.f);
        }
        // GEMM2: this lane's channel-quad kq*4..+4
        #pragma unroll
        for (int jj = 0; jj < 8; jj++) {
            float4 wv = *(const float4*)&W1[((jbase + jj) << 4) + (kq << 2)];
            #pragma unroll
            for (int i = 0; i < 4; i++) {
                dx[i][0] = fmaf(h[i][jj], wv.x, dx[i][0]);
                dx[i][1] = fmaf(h[i][jj], wv.y, dx[i][1]);
                dx[i][2] = fmaf(h[i][jj], wv.z, dx[i][2]);
                dx[i][3] = fmaf(h[i][jj], wv.w, dx[i][3]);
            }
        }

        // stage chunk jc+1 into the other buffer; issue chunk jc+2 loads
        if (jc < 7) {
            *(float4*)&wwr[wbase      ] = st0;
            *(float4*)&wwr[wbase +  36] = st1;
            *(float4*)&wwr[wbase +  72] = st2;
            *(float4*)&wwr[wbase + 108] = st3;
            if (jc < 6) {
                const float* pN = pW + ((jc + 2) << 5);
                st0 = *(const float4*)(pN);
                st1 = *(const float4*)(pN +  8192);
                st2 = *(const float4*)(pN + 16384);
                st3 = *(const float4*)(pN + 24576);
            }
            __syncthreads();   // single barrier per chunk
        }
    }

    // reduce dx over the 4 jg lanes (bits 2-3)
    #pragma unroll
    for (int i = 0; i < 4; i++)
        #pragma unroll
        for (int c = 0; c < 4; c++) {
            dx[i][c] += __shfl_xor(dx[i][c], 4);
            dx[i][c] += __shfl_xor(dx[i][c], 8);
        }

    // writer: pixel 4quad+jg, channels kq*4..+4
    float o0 = jg==0?dx[0][0] : jg==1?dx[1][0] : jg==2?dx[2][0] : dx[3][0];
    float o1 = jg==0?dx[0][1] : jg==1?dx[1][1] : jg==2?dx[2][1] : dx[3][1];
    float o2 = jg==0?dx[0][2] : jg==1?dx[1][2] : jg==2?dx[2][2] : dx[3][2];
    float o3 = jg==0?dx[0][3] : jg==1?dx[1][3] : jg==2?dx[2][3] : dx[3][3];

    const int pw  = p0px + jg;
    const int ppy = pw >> 3, ppx = pw & 7;
    const int pix2 = (b << 16) + ((ty0 + ppy) << 8) + (tx0 + ppx);
    float fire = (stoch_s[pix2] > 0.5f) ? 1.f : 0.f;
    float4 xc2 = *(const float4*)&perc[pw*PST + (kq << 2)];
    float4 xn;
    xn.x = fmaf(fire, o0, xc2.x);
    xn.y = fmaf(fire, o1, xc2.y);
    xn.z = fmaf(fire, o2, xc2.z);
    xn.w = fmaf(fire, o3, xc2.w);
    *(float4*)&xmid[((size_t)pix2 << 4) + (kq << 2)] = xn;
    if (kq == 0) alpha_out[pix2] = xn.w;   // channel 3
}

// In-place life masking: reads alpha_new from the separate plane (race-free).
__global__ void step_mask(float* __restrict__ xbuf,
                          const float* __restrict__ alpha,
                          const float* __restrict__ prelife,
                          const float* __restrict__ valid) {
    int pix = blockIdx.x * 256 + threadIdx.x;
    int b = pix >> 16;
    int y = (pix >> 8) & 255;
    int x = pix & 255;
    float m = -INFINITY;
    #pragma unroll
    for (int dy = -1; dy <= 1; dy++) {
        #pragma unroll
        for (int dxo = -1; dxo <= 1; dxo++) {
            int yy = y + dy, xx = x + dxo;
            if ((unsigned)yy < 256u && (unsigned)xx < 256u)
                m = fmaxf(m, alpha[(b << 16) + (yy << 8) + xx]);
        }
    }
    float life = (prelife[pix] != 0.f && m > 0.1f) ? 1.f : 0.f;
    float s = life * valid[pix];
    float4* xp = (float4*)&xbuf[(size_t)pix << 4];
    #pragma unroll
    for (int i = 0; i < 4; i++) {
        float4 v = xp[i];
        v.x *= s; v.y *= s; v.z *= s; v.w *= s;
        xp[i] = v;
    }
}

extern "C" void kernel_launch(void* const* d_in, const int* in_sizes, int n_in,
                              void* d_out, int out_size, void* d_ws, size_t ws_size,
                              hipStream_t stream) {
    const float* x0    = (const float*)d_in[0];
    const float* valid = (const float*)d_in[1];
    const float* stoch = (const float*)d_in[2];
    const float* W0    = (const float*)d_in[3];
    const float* b0    = (const float*)d_in[4];
    const float* W1    = (const float*)d_in[5];

    float* ws      = (float*)d_ws;
    float* xA      = ws;                 // 8388608 floats
    float* alpha   = ws + 8388608;       // 524288
    float* prelife = ws + 8912896;       // 524288
    float* filt    = ws + 9437184;       // 294 (+pad)
    float* out     = (float*)d_out;

    init_kernel<<<1, 64, 0, stream>>>(W0, filt);

    const float* src = x0;
    for (int k = 1; k <= 16; k++) {
        float* dst = (k & 1) ? xA : out;   // step 16 (even) lands in d_out
        step_main<<<dim3(32,32,8), 256, 0, stream>>>(
            src, dst, alpha, prelife, filt, W0, b0, W1,
            stoch + (size_t)(k-1)*NPIX);
        step_mask<<<NPIX/256, 256, 0, stream>>>(dst, alpha, prelife, valid);
        src = dst;
    }
}

// Round 17
// 18466.953 us; speedup vs baseline: 2.4109x; 2.4109x over previous
//
#include <hip/hip_runtime.h>
#include <math.h>

// NCA: B=8, H=W=256, C=16, 16 steps. fp32.
// R16 post-mortem: NO launch_bounds != big register budget — hipcc default
// (1024-thr assumption) capped VGPR at 64 -> pv-hoist spilled (FETCH x8.6).
// R6's "256 regs" was just a ~70-live kernel. The pv-hoist was never tested
// with registers.
// R17 = R16 + __launch_bounds__(256, 1): min 1 wave/SIMD -> VGPR cap 256.
// Occupancy unchanged (LDS-capped at 2 blocks/CU); ~220 live fits.

#define HW 256
#define NPIX (8*HW*HW)   // 524288
#define PST 140          // perc row stride (floats)

__device__ __forceinline__ float4 f4max(float4 a, float4 b) {
    return make_float4(fmaxf(a.x,b.x), fmaxf(a.y,b.y), fmaxf(a.z,b.z), fmaxf(a.w,b.w));
}

// Precompute sobel bank (6 filters, 7x7, normalized).
__global__ void init_kernel(const float* __restrict__ W0,
                            float* __restrict__ filt) {
    int t = blockIdx.x * blockDim.x + threadIdx.x;
    if (t < 6) {
        int f = t;
        int size = 3 + 2*(f >> 1);
        int p0 = (7 - size) >> 1;
        int isY = f & 1;
        float vals[49];
        float norm = 0.f;
        for (int a = 0; a < 7; a++) {
            for (int b = 0; b < 7; b++) {
                float v = 0.f;
                if (a >= p0 && a < p0+size && b >= p0 && b < p0+size) {
                    float fy = (float)(a - 3), fx = (float)(b - 3);
                    float den = fx*fx + fy*fy;
                    if (den == 0.f) den = 1.f;
                    v = (isY ? fy : fx) / den;
                }
                vals[a*7+b] = v;
                norm += fabsf(v);
            }
        }
        float inv = 1.f / norm;
        for (int i = 0; i < 49; i++) filt[f*49 + i] = vals[i] * inv;
    }
}

// One 8x8 pixel tile per block, 256 threads.
__launch_bounds__(256, 1)
__global__ void step_main(const float* __restrict__ x,
                          float* __restrict__ xmid,
                          float* __restrict__ alpha_out,
                          float* __restrict__ prelife_out,
                          const float* __restrict__ filt_g,
                          const float* __restrict__ W0,
                          const float* __restrict__ b0,
                          const float* __restrict__ W1,
                          const float* __restrict__ stoch_s) {
    // carve: phase1 xs [0,3920) + filt [3920,4214)
    //        phase2 w0sA [0,4608) | w0sB [4608,9216)
    //        perc [9216,18176)   -> 72704 B, 2 blocks/CU
    __shared__ float smem[18176];
    float* xs     = smem;          // 14*14*20 = 3920 (phase 1 only)
    float* filt_s = smem + 3920;   // 294 (phase 1 only)
    float* w0sA   = smem;          // 128x36 (phase 2)
    float* w0sB   = smem + 4608;   // 128x36 (phase 2)
    float* perc   = smem + 9216;   // 64 x 140

    const int t   = threadIdx.x;
    const int b   = blockIdx.z;
    const int ty0 = blockIdx.y * 8;
    const int tx0 = blockIdx.x * 8;

    // T14 prologue: issue chunk-0 W0 loads NOW; they land during phase 1.
    const float* pW   = W0 + ((t >> 3) << 8) + ((t & 7) << 2);
    const int   wbase = (t >> 3) * 144 + ((t & 7) << 2);
    float4 st0 = *(const float4*)(pW);
    float4 st1 = *(const float4*)(pW +  8192);
    float4 st2 = *(const float4*)(pW + 16384);
    float4 st3 = *(const float4*)(pW + 24576);

    for (int i = t; i < 294; i += 256) filt_s[i] = filt_g[i];

    // stage x tile + halo (zero pad = conv's zero padding)
    for (int v = t; v < 784; v += 256) {          // 14*14*4 float4s
        int c4  = v & 3;
        int cell = v >> 2;
        int ly = cell / 14;
        int lx = cell - ly*14;
        int gy = ty0 + ly - 3, gx = tx0 + lx - 3;
        float4 val = make_float4(0.f,0.f,0.f,0.f);
        if ((unsigned)gy < 256u && (unsigned)gx < 256u)
            val = *(const float4*)&x[((((b<<8) + gy)<<8) + gx)*16 + (c4<<2)];
        *(float4*)&xs[cell*20 + (c4<<2)] = val;
    }
    __syncthreads();

    {   // ---- phase 1: sparse conv + pools -> perc ----
        const int p  = t & 63;
        const int q  = t >> 6;
        const int py = p >> 3, px1 = p & 7;
        const int gy = ty0 + py, gx = tx0 + px1;
        const int q4 = q << 2;

        float4 y4[6];
        #pragma unroll
        for (int f = 0; f < 6; f++) y4[f] = make_float4(0.f,0.f,0.f,0.f);

        #pragma unroll
        for (int a = 0; a < 7; a++) {
            #pragma unroll
            for (int bb = 0; bb < 7; bb++) {
                float4 xv = *(const float4*)&xs[((py+a)*14 + (px1+bb))*20 + q4];
                {   // f=4,5: full 7x7
                    float w4 = filt_s[4*49 + a*7 + bb];
                    float w5 = filt_s[5*49 + a*7 + bb];
                    y4[4].x = fmaf(w4, xv.x, y4[4].x); y4[4].y = fmaf(w4, xv.y, y4[4].y);
                    y4[4].z = fmaf(w4, xv.z, y4[4].z); y4[4].w = fmaf(w4, xv.w, y4[4].w);
                    y4[5].x = fmaf(w5, xv.x, y4[5].x); y4[5].y = fmaf(w5, xv.y, y4[5].y);
                    y4[5].z = fmaf(w5, xv.z, y4[5].z); y4[5].w = fmaf(w5, xv.w, y4[5].w);
                }
                if (a >= 1 && a <= 5 && bb >= 1 && bb <= 5) {   // f=2,3: 5x5
                    float w2 = filt_s[2*49 + a*7 + bb];
                    float w3 = filt_s[3*49 + a*7 + bb];
                    y4[2].x = fmaf(w2, xv.x, y4[2].x); y4[2].y = fmaf(w2, xv.y, y4[2].y);
                    y4[2].z = fmaf(w2, xv.z, y4[2].z); y4[2].w = fmaf(w2, xv.w, y4[2].w);
                    y4[3].x = fmaf(w3, xv.x, y4[3].x); y4[3].y = fmaf(w3, xv.y, y4[3].y);
                    y4[3].z = fmaf(w3, xv.z, y4[3].z); y4[3].w = fmaf(w3, xv.w, y4[3].w);
                }
                if (a >= 2 && a <= 4 && bb >= 2 && bb <= 4) {   // f=0,1: 3x3
                    float w0 = filt_s[0*49 + a*7 + bb];
                    float w1 = filt_s[1*49 + a*7 + bb];
                    y4[0].x = fmaf(w0, xv.x, y4[0].x); y4[0].y = fmaf(w0, xv.y, y4[0].y);
                    y4[0].z = fmaf(w0, xv.z, y4[0].z); y4[0].w = fmaf(w0, xv.w, y4[0].w);
                    y4[1].x = fmaf(w1, xv.x, y4[1].x); y4[1].y = fmaf(w1, xv.y, y4[1].y);
                    y4[1].z = fmaf(w1, xv.z, y4[1].z); y4[1].w = fmaf(w1, xv.w, y4[1].w);
                }
            }
        }
        float4 m5 = make_float4(-INFINITY,-INFINITY,-INFINITY,-INFINITY);
        #pragma unroll
        for (int dy = -2; dy <= 2; dy++) {
            #pragma unroll
            for (int dx2 = -2; dx2 <= 2; dx2++) {
                if ((unsigned)(gy+dy) < 256u && (unsigned)(gx+dx2) < 256u)
                    m5 = f4max(m5, *(const float4*)&xs[((py+3+dy)*14 + (px1+3+dx2))*20 + q4]);
            }
        }
        // perc channel c stored at (c>>5)*36 + (c&31)
        float4 xc = *(const float4*)&xs[((py+3)*14 + (px1+3))*20 + q4];
        *(float4*)&perc[p*PST + q4] = xc;
        const int offY[6] = {16, 36, 52, 72, 88, 108};
        #pragma unroll
        for (int f = 0; f < 6; f++)
            *(float4*)&perc[p*PST + offY[f] + q4] = y4[f];
        *(float4*)&perc[p*PST + 124 + q4] = m5;

        if (q == 0) {
            float pre = -INFINITY;
            #pragma unroll
            for (int dy = -1; dy <= 1; dy++) {
                #pragma unroll
                for (int dx2 = -1; dx2 <= 1; dx2++) {
                    if ((unsigned)(gy+dy) < 256u && (unsigned)(gx+dx2) < 256u)
                        pre = fmaxf(pre, xs[((py+3+dy)*14 + (px1+3+dx2))*20 + 3]);
                }
            }
            prelife_out[(b << 16) + (gy << 8) + gx] = (pre > 0.1f) ? 1.f : 0.f;
        }
    }
    __syncthreads();   // xs reads done; perc published. xs region -> w0sA.

    // ---- phase 2: MLP, double-buffered w0s, perc hoisted to registers ----
    const int kq   = t & 3;
    const int jg   = (t >> 2) & 3;
    const int quad = t >> 4;        // owns 4 consecutive px {4quad..4quad+3}
    const int jg8  = jg << 3;
    const int p0px = quad << 2;

    const float* pp0 = &perc[(p0px    ) * PST + kq*36];
    const float* pp1 = &perc[(p0px + 1) * PST + kq*36];
    const float* pp2 = &perc[(p0px + 2) * PST + kq*36];
    const float* pp3 = &perc[(p0px + 3) * PST + kq*36];

    // jc-invariant perc slice -> registers (32 b128, once; literal indices)
    float4 pv0[8], pv1[8], pv2[8], pv3[8];
    #pragma unroll
    for (int r = 0; r < 8; r++) {
        pv0[r] = *(const float4*)&pp0[r << 2];
        pv1[r] = *(const float4*)&pp1[r << 2];
        pv2[r] = *(const float4*)&pp2[r << 2];
        pv3[r] = *(const float4*)&pp3[r << 2];
    }

    float dx[4][4];
    #pragma unroll
    for (int i = 0; i < 4; i++)
        #pragma unroll
        for (int c = 0; c < 4; c++) dx[i][c] = 0.f;

    // prologue: write chunk 0 -> A; issue chunk-1 loads
    *(float4*)&w0sA[wbase      ] = st0;
    *(float4*)&w0sA[wbase +  36] = st1;
    *(float4*)&w0sA[wbase +  72] = st2;
    *(float4*)&w0sA[wbase + 108] = st3;
    st0 = *(const float4*)(pW + 32);
    st1 = *(const float4*)(pW + 32 +  8192);
    st2 = *(const float4*)(pW + 32 + 16384);
    st3 = *(const float4*)(pW + 32 + 24576);
    __syncthreads();   // A visible

    #pragma unroll 1
    for (int jc = 0; jc < 8; jc++) {
        const float* wrd = (jc & 1) ? w0sB : w0sA;   // chunk jc
        float*       wwr = (jc & 1) ? w0sA : w0sB;   // chunk jc+1

        float h[4][8];
        #pragma unroll
        for (int i = 0; i < 4; i++)
            #pragma unroll
            for (int jj = 0; jj < 8; jj++) h[i][jj] = 0.f;

        #pragma unroll
        for (int k4 = 0; k4 < 32; k4 += 4) {
            float4 pA0 = pv0[k4 >> 2];
            float4 pA1 = pv1[k4 >> 2];
            float4 pA2 = pv2[k4 >> 2];
            float4 pA3 = pv3[k4 >> 2];
            #pragma unroll
            for (int kk = 0; kk < 4; kk++) {
                float a0 = kk==0?pA0.x : kk==1?pA0.y : kk==2?pA0.z : pA0.w;
                float a1 = kk==0?pA1.x : kk==1?pA1.y : kk==2?pA1.z : pA1.w;
                float a2 = kk==0?pA2.x : kk==1?pA2.y : kk==2?pA2.z : pA2.w;
                float a3 = kk==0?pA3.x : kk==1?pA3.y : kk==2?pA3.z : pA3.w;
                const float* wr = &wrd[((k4 + kk)*4 + kq)*36 + jg8];
                float4 wA = *(const float4*)wr;
                float4 wB = *(const float4*)(wr + 4);
                #pragma unroll
                for (int i = 0; i < 4; i++) {
                    float ai = i==0?a0 : i==1?a1 : i==2?a2 : a3;
                    h[i][0] = fmaf(ai, wA.x, h[i][0]);
                    h[i][1] = fmaf(ai, wA.y, h[i][1]);
                    h[i][2] = fmaf(ai, wA.z, h[i][2]);
                    h[i][3] = fmaf(ai, wA.w, h[i][3]);
                    h[i][4] = fmaf(ai, wB.x, h[i][4]);
                    h[i][5] = fmaf(ai, wB.y, h[i][5]);
                    h[i][6] = fmaf(ai, wB.z, h[i][6]);
                    h[i][7] = fmaf(ai, wB.w, h[i][7]);
                }
            }
        }
        // reduce h over the 4 kq lanes (bits 0-1)
        #pragma unroll
        for (int i = 0; i < 4; i++)
            #pragma unroll
            for (int jj = 0; jj < 8; jj++) {
                h[i][jj] += __shfl_xor(h[i][jj], 1);
                h[i][jj] += __shfl_xor(h[i][jj], 2);
            }
        // bias + relu
        const int jbase = (jc << 5) + jg8;
        float4 bA = *(const float4*)&b0[jbase];
        float4 bB = *(const float4*)&b0[jbase + 4];
        #pragma unroll
        for (int i = 0; i < 4; i++) {
            h[i][0] = fmaxf(h[i][0] + bA.x, 0.f);
            h[i][1] = fmaxf(h[i][1] + bA.y, 0.f);
            h[i][2] = fmaxf(h[i][2] + bA.z, 0.f);
            h[i][3] = fmaxf(h[i][3] + bA.w, 0.f);
            h[i][4] = fmaxf(h[i][4] + bB.x, 0.f);
            h[i][5] = fmaxf(h[i][5] + bB.y, 0.f);
            h[i][6] = fmaxf(h[i][6] + bB.z, 0.f);
            h[i][7] = fmaxf(h[i][7] + bB.w, 0.f);
        }
        // GEMM2: this lane's channel-quad kq*4..+4
        #pragma unroll
        for (int jj = 0; jj < 8; jj++) {
            float4 wv = *(const float4*)&W1[((jbase + jj) << 4) + (kq << 2)];
            #pragma unroll
            for (int i = 0; i < 4; i++) {
                dx[i][0] = fmaf(h[i][jj], wv.x, dx[i][0]);
                dx[i][1] = fmaf(h[i][jj], wv.y, dx[i][1]);
                dx[i][2] = fmaf(h[i][jj], wv.z, dx[i][2]);
                dx[i][3] = fmaf(h[i][jj], wv.w, dx[i][3]);
            }
        }

        // stage chunk jc+1 into the other buffer; issue chunk jc+2 loads
        if (jc < 7) {
            *(float4*)&wwr[wbase      ] = st0;
            *(float4*)&wwr[wbase +  36] = st1;
            *(float4*)&wwr[wbase +  72] = st2;
            *(float4*)&wwr[wbase + 108] = st3;
            if (jc < 6) {
                const float* pN = pW + ((jc + 2) << 5);
                st0 = *(const float4*)(pN);
                st1 = *(const float4*)(pN +  8192);
                st2 = *(const float4*)(pN + 16384);
                st3 = *(const float4*)(pN + 24576);
            }
            __syncthreads();   // single barrier per chunk
        }
    }

    // reduce dx over the 4 jg lanes (bits 2-3)
    #pragma unroll
    for (int i = 0; i < 4; i++)
        #pragma unroll
        for (int c = 0; c < 4; c++) {
            dx[i][c] += __shfl_xor(dx[i][c], 4);
            dx[i][c] += __shfl_xor(dx[i][c], 8);
        }

    // writer: pixel 4quad+jg, channels kq*4..+4
    float o0 = jg==0?dx[0][0] : jg==1?dx[1][0] : jg==2?dx[2][0] : dx[3][0];
    float o1 = jg==0?dx[0][1] : jg==1?dx[1][1] : jg==2?dx[2][1] : dx[3][1];
    float o2 = jg==0?dx[0][2] : jg==1?dx[1][2] : jg==2?dx[2][2] : dx[3][2];
    float o3 = jg==0?dx[0][3] : jg==1?dx[1][3] : jg==2?dx[2][3] : dx[3][3];

    const int pw  = p0px + jg;
    const int ppy = pw >> 3, ppx = pw & 7;
    const int pix2 = (b << 16) + ((ty0 + ppy) << 8) + (tx0 + ppx);
    float fire = (stoch_s[pix2] > 0.5f) ? 1.f : 0.f;
    float4 xc2 = *(const float4*)&perc[pw*PST + (kq << 2)];
    float4 xn;
    xn.x = fmaf(fire, o0, xc2.x);
    xn.y = fmaf(fire, o1, xc2.y);
    xn.z = fmaf(fire, o2, xc2.z);
    xn.w = fmaf(fire, o3, xc2.w);
    *(float4*)&xmid[((size_t)pix2 << 4) + (kq << 2)] = xn;
    if (kq == 0) alpha_out[pix2] = xn.w;   // channel 3
}

// In-place life masking: reads alpha_new from the separate plane (race-free).
__global__ void step_mask(float* __restrict__ xbuf,
                          const float* __restrict__ alpha,
                          const float* __restrict__ prelife,
                          const float* __restrict__ valid) {
    int pix = blockIdx.x * 256 + threadIdx.x;
    int b = pix >> 16;
    int y = (pix >> 8) & 255;
    int x = pix & 255;
    float m = -INFINITY;
    #pragma unroll
    for (int dy = -1; dy <= 1; dy++) {
        #pragma unroll
        for (int dxo = -1; dxo <= 1; dxo++) {
            int yy = y + dy, xx = x + dxo;
            if ((unsigned)yy < 256u && (unsigned)xx < 256u)
                m = fmaxf(m, alpha[(b << 16) + (yy << 8) + xx]);
        }
    }
    float life = (prelife[pix] != 0.f && m > 0.1f) ? 1.f : 0.f;
    float s = life * valid[pix];
    float4* xp = (float4*)&xbuf[(size_t)pix << 4];
    #pragma unroll
    for (int i = 0; i < 4; i++) {
        float4 v = xp[i];
        v.x *= s; v.y *= s; v.z *= s; v.w *= s;
        xp[i] = v;
    }
}

extern "C" void kernel_launch(void* const* d_in, const int* in_sizes, int n_in,
                              void* d_out, int out_size, void* d_ws, size_t ws_size,
                              hipStream_t stream) {
    const float* x0    = (const float*)d_in[0];
    const float* valid = (const float*)d_in[1];
    const float* stoch = (const float*)d_in[2];
    const float* W0    = (const float*)d_in[3];
    const float* b0    = (const float*)d_in[4];
    const float* W1    = (const float*)d_in[5];

    float* ws      = (float*)d_ws;
    float* xA      = ws;                 // 8388608 floats
    float* alpha   = ws + 8388608;       // 524288
    float* prelife = ws + 8912896;       // 524288
    float* filt    = ws + 9437184;       // 294 (+pad)
    float* out     = (float*)d_out;

    init_kernel<<<1, 64, 0, stream>>>(W0, filt);

    const float* src = x0;
    for (int k = 1; k <= 16; k++) {
        float* dst = (k & 1) ? xA : out;   // step 16 (even) lands in d_out
        step_main<<<dim3(32,32,8), 256, 0, stream>>>(
            src, dst, alpha, prelife, filt, W0, b0, W1,
            stoch + (size_t)(k-1)*NPIX);
        step_mask<<<NPIX/256, 256, 0, stream>>>(dst, alpha, prelife, valid);
        src = dst;
    }
}

// Round 18
// 13868.919 us; speedup vs baseline: 3.2102x; 1.3315x over previous
//
#include <hip/hip_runtime.h>
#include <math.h>

// NCA: B=8, H=W=256, C=16, 16 steps. fp32.
// R17 post-mortem: pv-hoist landed (VGPR 208, no spill) but cost a block/CU
// (2->1, occ 12%) -> net loss. Reverted. Shuffles confirmed as ds-ops
// (conflict counter 8.8e7 w/ shfl vs 2.2e7 without).
// R18 = R15 + DPP kq-reduction: masks 1,2 are intra-quad -> v_add with
// quad_perm DPP (0xB1, 0x4E) on the VALU pipe; removes 512 LDS-pipe ops
// per thread. Final dx reduce (xor 4,8; 32 ops once) stays shfl.

#define HW 256
#define NPIX (8*HW*HW)   // 524288
#define PST 140          // perc row stride (floats)

__device__ __forceinline__ float4 f4max(float4 a, float4 b) {
    return make_float4(fmaxf(a.x,b.x), fmaxf(a.y,b.y), fmaxf(a.z,b.z), fmaxf(a.w,b.w));
}
// intra-quad exchanges on the VALU pipe (DPP quad_perm), not LDS
__device__ __forceinline__ float dpp_xor1(float v) {   // lanes 0<->1, 2<->3
    return __int_as_float(__builtin_amdgcn_update_dpp(
        0, __float_as_int(v), 0xB1 /*quad_perm 1,0,3,2*/, 0xF, 0xF, true));
}
__device__ __forceinline__ float dpp_xor2(float v) {   // lanes 0<->2, 1<->3
    return __int_as_float(__builtin_amdgcn_update_dpp(
        0, __float_as_int(v), 0x4E /*quad_perm 2,3,0,1*/, 0xF, 0xF, true));
}

// Precompute sobel bank (6 filters, 7x7, normalized).
__global__ void init_kernel(const float* __restrict__ W0,
                            float* __restrict__ filt) {
    int t = blockIdx.x * blockDim.x + threadIdx.x;
    if (t < 6) {
        int f = t;
        int size = 3 + 2*(f >> 1);
        int p0 = (7 - size) >> 1;
        int isY = f & 1;
        float vals[49];
        float norm = 0.f;
        for (int a = 0; a < 7; a++) {
            for (int b = 0; b < 7; b++) {
                float v = 0.f;
                if (a >= p0 && a < p0+size && b >= p0 && b < p0+size) {
                    float fy = (float)(a - 3), fx = (float)(b - 3);
                    float den = fx*fx + fy*fy;
                    if (den == 0.f) den = 1.f;
                    v = (isY ? fy : fx) / den;
                }
                vals[a*7+b] = v;
                norm += fabsf(v);
            }
        }
        float inv = 1.f / norm;
        for (int i = 0; i < 49; i++) filt[f*49 + i] = vals[i] * inv;
    }
}

// One 8x8 pixel tile per block, 256 threads.
__launch_bounds__(256, 2)
__global__ void step_main(const float* __restrict__ x,
                          float* __restrict__ xmid,
                          float* __restrict__ alpha_out,
                          float* __restrict__ prelife_out,
                          const float* __restrict__ filt_g,
                          const float* __restrict__ W0,
                          const float* __restrict__ b0,
                          const float* __restrict__ W1,
                          const float* __restrict__ stoch_s) {
    // carve: phase1 xs [0,3920) + filt [3920,4214)
    //        phase2 w0sA [0,4608) | w0sB [4608,9216)
    //        perc [9216,18176)   -> 72704 B, 2 blocks/CU
    __shared__ float smem[18176];
    float* xs     = smem;          // 14*14*20 = 3920 (phase 1 only)
    float* filt_s = smem + 3920;   // 294 (phase 1 only)
    float* w0sA   = smem;          // 128x36 (phase 2)
    float* w0sB   = smem + 4608;   // 128x36 (phase 2)
    float* perc   = smem + 9216;   // 64 x 140

    const int t   = threadIdx.x;
    const int b   = blockIdx.z;
    const int ty0 = blockIdx.y * 8;
    const int tx0 = blockIdx.x * 8;

    // T14 prologue: issue chunk-0 W0 loads NOW; they land during phase 1.
    const float* pW   = W0 + ((t >> 3) << 8) + ((t & 7) << 2);
    const int   wbase = (t >> 3) * 144 + ((t & 7) << 2);
    float4 st0 = *(const float4*)(pW);
    float4 st1 = *(const float4*)(pW +  8192);
    float4 st2 = *(const float4*)(pW + 16384);
    float4 st3 = *(const float4*)(pW + 24576);

    for (int i = t; i < 294; i += 256) filt_s[i] = filt_g[i];

    // stage x tile + halo (zero pad = conv's zero padding)
    for (int v = t; v < 784; v += 256) {          // 14*14*4 float4s
        int c4  = v & 3;
        int cell = v >> 2;
        int ly = cell / 14;
        int lx = cell - ly*14;
        int gy = ty0 + ly - 3, gx = tx0 + lx - 3;
        float4 val = make_float4(0.f,0.f,0.f,0.f);
        if ((unsigned)gy < 256u && (unsigned)gx < 256u)
            val = *(const float4*)&x[((((b<<8) + gy)<<8) + gx)*16 + (c4<<2)];
        *(float4*)&xs[cell*20 + (c4<<2)] = val;
    }
    __syncthreads();

    {   // ---- phase 1: sparse conv + pools -> perc ----
        const int p  = t & 63;
        const int q  = t >> 6;
        const int py = p >> 3, px1 = p & 7;
        const int gy = ty0 + py, gx = tx0 + px1;
        const int q4 = q << 2;

        float4 y4[6];
        #pragma unroll
        for (int f = 0; f < 6; f++) y4[f] = make_float4(0.f,0.f,0.f,0.f);

        #pragma unroll
        for (int a = 0; a < 7; a++) {
            #pragma unroll
            for (int bb = 0; bb < 7; bb++) {
                float4 xv = *(const float4*)&xs[((py+a)*14 + (px1+bb))*20 + q4];
                {   // f=4,5: full 7x7
                    float w4 = filt_s[4*49 + a*7 + bb];
                    float w5 = filt_s[5*49 + a*7 + bb];
                    y4[4].x = fmaf(w4, xv.x, y4[4].x); y4[4].y = fmaf(w4, xv.y, y4[4].y);
                    y4[4].z = fmaf(w4, xv.z, y4[4].z); y4[4].w = fmaf(w4, xv.w, y4[4].w);
                    y4[5].x = fmaf(w5, xv.x, y4[5].x); y4[5].y = fmaf(w5, xv.y, y4[5].y);
                    y4[5].z = fmaf(w5, xv.z, y4[5].z); y4[5].w = fmaf(w5, xv.w, y4[5].w);
                }
                if (a >= 1 && a <= 5 && bb >= 1 && bb <= 5) {   // f=2,3: 5x5
                    float w2 = filt_s[2*49 + a*7 + bb];
                    float w3 = filt_s[3*49 + a*7 + bb];
                    y4[2].x = fmaf(w2, xv.x, y4[2].x); y4[2].y = fmaf(w2, xv.y, y4[2].y);
                    y4[2].z = fmaf(w2, xv.z, y4[2].z); y4[2].w = fmaf(w2, xv.w, y4[2].w);
                    y4[3].x = fmaf(w3, xv.x, y4[3].x); y4[3].y = fmaf(w3, xv.y, y4[3].y);
                    y4[3].z = fmaf(w3, xv.z, y4[3].z); y4[3].w = fmaf(w3, xv.w, y4[3].w);
                }
                if (a >= 2 && a <= 4 && bb >= 2 && bb <= 4) {   // f=0,1: 3x3
                    float w0 = filt_s[0*49 + a*7 + bb];
                    float w1 = filt_s[1*49 + a*7 + bb];
                    y4[0].x = fmaf(w0, xv.x, y4[0].x); y4[0].y = fmaf(w0, xv.y, y4[0].y);
                    y4[0].z = fmaf(w0, xv.z, y4[0].z); y4[0].w = fmaf(w0, xv.w, y4[0].w);
                    y4[1].x = fmaf(w1, xv.x, y4[1].x); y4[1].y = fmaf(w1, xv.y, y4[1].y);
                    y4[1].z = fmaf(w1, xv.z, y4[1].z); y4[1].w = fmaf(w1, xv.w, y4[1].w);
                }
            }
        }
        float4 m5 = make_float4(-INFINITY,-INFINITY,-INFINITY,-INFINITY);
        #pragma unroll
        for (int dy = -2; dy <= 2; dy++) {
            #pragma unroll
            for (int dx2 = -2; dx2 <= 2; dx2++) {
                if ((unsigned)(gy+dy) < 256u && (unsigned)(gx+dx2) < 256u)
                    m5 = f4max(m5, *(const float4*)&xs[((py+3+dy)*14 + (px1+3+dx2))*20 + q4]);
            }
        }
        // perc channel c stored at (c>>5)*36 + (c&31)
        float4 xc = *(const float4*)&xs[((py+3)*14 + (px1+3))*20 + q4];
        *(float4*)&perc[p*PST + q4] = xc;
        const int offY[6] = {16, 36, 52, 72, 88, 108};
        #pragma unroll
        for (int f = 0; f < 6; f++)
            *(float4*)&perc[p*PST + offY[f] + q4] = y4[f];
        *(float4*)&perc[p*PST + 124 + q4] = m5;

        if (q == 0) {
            float pre = -INFINITY;
            #pragma unroll
            for (int dy = -1; dy <= 1; dy++) {
                #pragma unroll
                for (int dx2 = -1; dx2 <= 1; dx2++) {
                    if ((unsigned)(gy+dy) < 256u && (unsigned)(gx+dx2) < 256u)
                        pre = fmaxf(pre, xs[((py+3+dy)*14 + (px1+3+dx2))*20 + 3]);
                }
            }
            prelife_out[(b << 16) + (gy << 8) + gx] = (pre > 0.1f) ? 1.f : 0.f;
        }
    }
    __syncthreads();   // xs reads done; perc published. xs region -> w0sA.

    // ---- phase 2: MLP, double-buffered w0s ----
    const int kq   = t & 3;
    const int jg   = (t >> 2) & 3;
    const int quad = t >> 4;        // owns 4 consecutive px {4quad..4quad+3}
    const int jg8  = jg << 3;
    const int p0px = quad << 2;

    const float* pp0 = &perc[(p0px    ) * PST + kq*36];
    const float* pp1 = &perc[(p0px + 1) * PST + kq*36];
    const float* pp2 = &perc[(p0px + 2) * PST + kq*36];
    const float* pp3 = &perc[(p0px + 3) * PST + kq*36];

    float dx[4][4];
    #pragma unroll
    for (int i = 0; i < 4; i++)
        #pragma unroll
        for (int c = 0; c < 4; c++) dx[i][c] = 0.f;

    // prologue: write chunk 0 -> A; issue chunk-1 loads
    *(float4*)&w0sA[wbase      ] = st0;
    *(float4*)&w0sA[wbase +  36] = st1;
    *(float4*)&w0sA[wbase +  72] = st2;
    *(float4*)&w0sA[wbase + 108] = st3;
    st0 = *(const float4*)(pW + 32);
    st1 = *(const float4*)(pW + 32 +  8192);
    st2 = *(const float4*)(pW + 32 + 16384);
    st3 = *(const float4*)(pW + 32 + 24576);
    __syncthreads();   // A visible

    #pragma unroll 1
    for (int jc = 0; jc < 8; jc++) {
        const float* wrd = (jc & 1) ? w0sB : w0sA;   // chunk jc
        float*       wwr = (jc & 1) ? w0sA : w0sB;   // chunk jc+1

        float h[4][8];
        #pragma unroll
        for (int i = 0; i < 4; i++)
            #pragma unroll
            for (int jj = 0; jj < 8; jj++) h[i][jj] = 0.f;

        #pragma unroll
        for (int k4 = 0; k4 < 32; k4 += 4) {
            float4 pA0 = *(const float4*)&pp0[k4];
            float4 pA1 = *(const float4*)&pp1[k4];
            float4 pA2 = *(const float4*)&pp2[k4];
            float4 pA3 = *(const float4*)&pp3[k4];
            #pragma unroll
            for (int kk = 0; kk < 4; kk++) {
                float a0 = kk==0?pA0.x : kk==1?pA0.y : kk==2?pA0.z : pA0.w;
                float a1 = kk==0?pA1.x : kk==1?pA1.y : kk==2?pA1.z : pA1.w;
                float a2 = kk==0?pA2.x : kk==1?pA2.y : kk==2?pA2.z : pA2.w;
                float a3 = kk==0?pA3.x : kk==1?pA3.y : kk==2?pA3.z : pA3.w;
                const float* wr = &wrd[((k4 + kk)*4 + kq)*36 + jg8];
                float4 wA = *(const float4*)wr;
                float4 wB = *(const float4*)(wr + 4);
                #pragma unroll
                for (int i = 0; i < 4; i++) {
                    float ai = i==0?a0 : i==1?a1 : i==2?a2 : a3;
                    h[i][0] = fmaf(ai, wA.x, h[i][0]);
                    h[i][1] = fmaf(ai, wA.y, h[i][1]);
                    h[i][2] = fmaf(ai, wA.z, h[i][2]);
                    h[i][3] = fmaf(ai, wA.w, h[i][3]);
                    h[i][4] = fmaf(ai, wB.x, h[i][4]);
                    h[i][5] = fmaf(ai, wB.y, h[i][5]);
                    h[i][6] = fmaf(ai, wB.z, h[i][6]);
                    h[i][7] = fmaf(ai, wB.w, h[i][7]);
                }
            }
        }
        // reduce h over the 4 kq lanes: DPP quad_perm (VALU pipe, no LDS)
        #pragma unroll
        for (int i = 0; i < 4; i++)
            #pragma unroll
            for (int jj = 0; jj < 8; jj++) {
                h[i][jj] += dpp_xor1(h[i][jj]);
                h[i][jj] += dpp_xor2(h[i][jj]);
            }
        // bias + relu
        const int jbase = (jc << 5) + jg8;
        float4 bA = *(const float4*)&b0[jbase];
        float4 bB = *(const float4*)&b0[jbase + 4];
        #pragma unroll
        for (int i = 0; i < 4; i++) {
            h[i][0] = fmaxf(h[i][0] + bA.x, 0.f);
            h[i][1] = fmaxf(h[i][1] + bA.y, 0.f);
            h[i][2] = fmaxf(h[i][2] + bA.z, 0.f);
            h[i][3] = fmaxf(h[i][3] + bA.w, 0.f);
            h[i][4] = fmaxf(h[i][4] + bB.x, 0.f);
            h[i][5] = fmaxf(h[i][5] + bB.y, 0.f);
            h[i][6] = fmaxf(h[i][6] + bB.z, 0.f);
            h[i][7] = fmaxf(h[i][7] + bB.w, 0.f);
        }
        // GEMM2: this lane's channel-quad kq*4..+4
        #pragma unroll
        for (int jj = 0; jj < 8; jj++) {
            float4 wv = *(const float4*)&W1[((jbase + jj) << 4) + (kq << 2)];
            #pragma unroll
            for (int i = 0; i < 4; i++) {
                dx[i][0] = fmaf(h[i][jj], wv.x, dx[i][0]);
                dx[i][1] = fmaf(h[i][jj], wv.y, dx[i][1]);
                dx[i][2] = fmaf(h[i][jj], wv.z, dx[i][2]);
                dx[i][3] = fmaf(h[i][jj], wv.w, dx[i][3]);
            }
        }

        // stage chunk jc+1 into the other buffer; issue chunk jc+2 loads
        if (jc < 7) {
            *(float4*)&wwr[wbase      ] = st0;
            *(float4*)&wwr[wbase +  36] = st1;
            *(float4*)&wwr[wbase +  72] = st2;
            *(float4*)&wwr[wbase + 108] = st3;
            if (jc < 6) {
                const float* pN = pW + ((jc + 2) << 5);
                st0 = *(const float4*)(pN);
                st1 = *(const float4*)(pN +  8192);
                st2 = *(const float4*)(pN + 16384);
                st3 = *(const float4*)(pN + 24576);
            }
            __syncthreads();   // single barrier per chunk
        }
    }

    // reduce dx over the 4 jg lanes (bits 2-3; once, keep shfl)
    #pragma unroll
    for (int i = 0; i < 4; i++)
        #pragma unroll
        for (int c = 0; c < 4; c++) {
            dx[i][c] += __shfl_xor(dx[i][c], 4);
            dx[i][c] += __shfl_xor(dx[i][c], 8);
        }

    // writer: pixel 4quad+jg, channels kq*4..+4
    float o0 = jg==0?dx[0][0] : jg==1?dx[1][0] : jg==2?dx[2][0] : dx[3][0];
    float o1 = jg==0?dx[0][1] : jg==1?dx[1][1] : jg==2?dx[2][1] : dx[3][1];
    float o2 = jg==0?dx[0][2] : jg==1?dx[1][2] : jg==2?dx[2][2] : dx[3][2];
    float o3 = jg==0?dx[0][3] : jg==1?dx[1][3] : jg==2?dx[2][3] : dx[3][3];

    const int pw  = p0px + jg;
    const int ppy = pw >> 3, ppx = pw & 7;
    const int pix2 = (b << 16) + ((ty0 + ppy) << 8) + (tx0 + ppx);
    float fire = (stoch_s[pix2] > 0.5f) ? 1.f : 0.f;
    float4 xc2 = *(const float4*)&perc[pw*PST + (kq << 2)];
    float4 xn;
    xn.x = fmaf(fire, o0, xc2.x);
    xn.y = fmaf(fire, o1, xc2.y);
    xn.z = fmaf(fire, o2, xc2.z);
    xn.w = fmaf(fire, o3, xc2.w);
    *(float4*)&xmid[((size_t)pix2 << 4) + (kq << 2)] = xn;
    if (kq == 0) alpha_out[pix2] = xn.w;   // channel 3
}

// In-place life masking: reads alpha_new from the separate plane (race-free).
__global__ void step_mask(float* __restrict__ xbuf,
                          const float* __restrict__ alpha,
                          const float* __restrict__ prelife,
                          const float* __restrict__ valid) {
    int pix = blockIdx.x * 256 + threadIdx.x;
    int b = pix >> 16;
    int y = (pix >> 8) & 255;
    int x = pix & 255;
    float m = -INFINITY;
    #pragma unroll
    for (int dy = -1; dy <= 1; dy++) {
        #pragma unroll
        for (int dxo = -1; dxo <= 1; dxo++) {
            int yy = y + dy, xx = x + dxo;
            if ((unsigned)yy < 256u && (unsigned)xx < 256u)
                m = fmaxf(m, alpha[(b << 16) + (yy << 8) + xx]);
        }
    }
    float life = (prelife[pix] != 0.f && m > 0.1f) ? 1.f : 0.f;
    float s = life * valid[pix];
    float4* xp = (float4*)&xbuf[(size_t)pix << 4];
    #pragma unroll
    for (int i = 0; i < 4; i++) {
        float4 v = xp[i];
        v.x *= s; v.y *= s; v.z *= s; v.w *= s;
        xp[i] = v;
    }
}

extern "C" void kernel_launch(void* const* d_in, const int* in_sizes, int n_in,
                              void* d_out, int out_size, void* d_ws, size_t ws_size,
                              hipStream_t stream) {
    const float* x0    = (const float*)d_in[0];
    const float* valid = (const float*)d_in[1];
    const float* stoch = (const float*)d_in[2];
    const float* W0    = (const float*)d_in[3];
    const float* b0    = (const float*)d_in[4];
    const float* W1    = (const float*)d_in[5];

    float* ws      = (float*)d_ws;
    float* xA      = ws;                 // 8388608 floats
    float* alpha   = ws + 8388608;       // 524288
    float* prelife = ws + 8912896;       // 524288
    float* filt    = ws + 9437184;       // 294 (+pad)
    float* out     = (float*)d_out;

    init_kernel<<<1, 64, 0, stream>>>(W0, filt);

    const float* src = x0;
    for (int k = 1; k <= 16; k++) {
        float* dst = (k & 1) ? xA : out;   // step 16 (even) lands in d_out
        step_main<<<dim3(32,32,8), 256, 0, stream>>>(
            src, dst, alpha, prelife, filt, W0, b0, W1,
            stoch + (size_t)(k-1)*NPIX);
        step_mask<<<NPIX/256, 256, 0, stream>>>(dst, alpha, prelife, valid);
        src = dst;
    }
}

// Round 19
// 13718.340 us; speedup vs baseline: 3.2454x; 1.0110x over previous
//
#include <hip/hip_runtime.h>
#include <math.h>

// NCA: B=8, H=W=256, C=16, 16 steps. fp32.
// R19: fused life-mask into halo staging (steps 2..16); prelife ping-pong
// uchar planes; alpha read from x channel 3 (alpha plane deleted); one final
// step_mask. Phase-2 = R18 (dbuf w0s + DPP kq-reduce).

#define HW 256
#define NPIX (8*HW*HW)   // 524288
#define PST 140          // perc row stride (floats)

__device__ __forceinline__ float4 f4max(float4 a, float4 b) {
    return make_float4(fmaxf(a.x,b.x), fmaxf(a.y,b.y), fmaxf(a.z,b.z), fmaxf(a.w,b.w));
}
__device__ __forceinline__ float dpp_xor1(float v) {   // lanes 0<->1, 2<->3
    return __int_as_float(__builtin_amdgcn_update_dpp(
        0, __float_as_int(v), 0xB1, 0xF, 0xF, true));
}
__device__ __forceinline__ float dpp_xor2(float v) {   // lanes 0<->2, 1<->3
    return __int_as_float(__builtin_amdgcn_update_dpp(
        0, __float_as_int(v), 0x4E, 0xF, 0xF, true));
}

__global__ void init_kernel(const float* __restrict__ W0,
                            float* __restrict__ filt) {
    int t = blockIdx.x * blockDim.x + threadIdx.x;
    if (t < 6) {
        int f = t;
        int size = 3 + 2*(f >> 1);
        int p0 = (7 - size) >> 1;
        int isY = f & 1;
        float vals[49];
        float norm = 0.f;
        for (int a = 0; a < 7; a++) {
            for (int b = 0; b < 7; b++) {
                float v = 0.f;
                if (a >= p0 && a < p0+size && b >= p0 && b < p0+size) {
                    float fy = (float)(a - 3), fx = (float)(b - 3);
                    float den = fx*fx + fy*fy;
                    if (den == 0.f) den = 1.f;
                    v = (isY ? fy : fx) / den;
                }
                vals[a*7+b] = v;
                norm += fabsf(v);
            }
        }
        float inv = 1.f / norm;
        for (int i = 0; i < 49; i++) filt[f*49 + i] = vals[i] * inv;
    }
}

__launch_bounds__(256, 2)
__global__ void step_main(const float* __restrict__ x,
                          float* __restrict__ xmid,
                          const unsigned char* __restrict__ prelife_in,
                          unsigned char* __restrict__ prelife_out,
                          const float* __restrict__ filt_g,
                          const float* __restrict__ W0,
                          const float* __restrict__ b0,
                          const float* __restrict__ W1,
                          const float* __restrict__ stoch_s,
                          const float* __restrict__ valid,
                          int apply_mask) {
    __shared__ float smem[18176];
    float* xs     = smem;          // 14*14*20 = 3920 (phase 1 only)
    float* filt_s = smem + 3920;   // 294 (phase 1 only)
    float* w0sA   = smem;          // 128x36 (phase 2)
    float* w0sB   = smem + 4608;   // 128x36 (phase 2)
    float* perc   = smem + 9216;   // 64 x 140

    const int t   = threadIdx.x;
    const int b   = blockIdx.z;
    const int ty0 = blockIdx.y * 8;
    const int tx0 = blockIdx.x * 8;

    const float* pW   = W0 + ((t >> 3) << 8) + ((t & 7) << 2);
    const int   wbase = (t >> 3) * 144 + ((t & 7) << 2);
    float4 st0 = *(const float4*)(pW);
    float4 st1 = *(const float4*)(pW +  8192);
    float4 st2 = *(const float4*)(pW + 16384);
    float4 st3 = *(const float4*)(pW + 24576);

    for (int i = t; i < 294; i += 256) filt_s[i] = filt_g[i];

    // stage x tile + halo with FUSED life-mask (bit-identical to step_mask)
    if (t < 196) {
        const int ly = t / 14, lx = t - ly*14;
        const int gy = ty0 + ly - 3, gx = tx0 + lx - 3;
        const bool inb = ((unsigned)gy < 256u) && ((unsigned)gx < 256u);
        float4 v0 = make_float4(0.f,0.f,0.f,0.f), v1 = v0, v2 = v0, v3 = v0;
        if (inb) {
            const int pix = (b << 16) + (gy << 8) + gx;
            const float* srcp = &x[(size_t)pix << 4];
            v0 = *(const float4*)(srcp);
            v1 = *(const float4*)(srcp + 4);
            v2 = *(const float4*)(srcp + 8);
            v3 = *(const float4*)(srcp + 12);
            if (apply_mask) {
                float m = -INFINITY;
                #pragma unroll
                for (int dy = -1; dy <= 1; dy++) {
                    #pragma unroll
                    for (int dxo = -1; dxo <= 1; dxo++) {
                        int yy = gy + dy, xx2 = gx + dxo;
                        if ((unsigned)yy < 256u && (unsigned)xx2 < 256u)
                            m = fmaxf(m, x[((size_t)((b<<16)+(yy<<8)+xx2) << 4) + 3]);
                    }
                }
                float s = (prelife_in[pix] != 0 && m > 0.1f) ? valid[pix] : 0.f;
                v0.x *= s; v0.y *= s; v0.z *= s; v0.w *= s;
                v1.x *= s; v1.y *= s; v1.z *= s; v1.w *= s;
                v2.x *= s; v2.y *= s; v2.z *= s; v2.w *= s;
                v3.x *= s; v3.y *= s; v3.z *= s; v3.w *= s;
            }
        }
        float* dstp = &xs[t * 20];
        *(float4*)(dstp)      = v0;
        *(float4*)(dstp + 4)  = v1;
        *(float4*)(dstp + 8)  = v2;
        *(float4*)(dstp + 12) = v3;
    }
    __syncthreads();

    {   // ---- phase 1: sparse conv + pools -> perc ----
        const int p  = t & 63;
        const int q  = t >> 6;
        const int py = p >> 3, px1 = p & 7;
        const int gy = ty0 + py, gx = tx0 + px1;
        const int q4 = q << 2;

        float4 y4[6];
        #pragma unroll
        for (int f = 0; f < 6; f++) y4[f] = make_float4(0.f,0.f,0.f,0.f);

        #pragma unroll
        for (int a = 0; a < 7; a++) {
            #pragma unroll
            for (int bb = 0; bb < 7; bb++) {
                float4 xv = *(const float4*)&xs[((py+a)*14 + (px1+bb))*20 + q4];
                {   // f=4,5: full 7x7
                    float w4 = filt_s[4*49 + a*7 + bb];
                    float w5 = filt_s[5*49 + a*7 + bb];
                    y4[4].x = fmaf(w4, xv.x, y4[4].x); y4[4].y = fmaf(w4, xv.y, y4[4].y);
                    y4[4].z = fmaf(w4, xv.z, y4[4].z); y4[4].w = fmaf(w4, xv.w, y4[4].w);
                    y4[5].x = fmaf(w5, xv.x, y4[5].x); y4[5].y = fmaf(w5, xv.y, y4[5].y);
                    y4[5].z = fmaf(w5, xv.z, y4[5].z); y4[5].w = fmaf(w5, xv.w, y4[5].w);
                }
                if (a >= 1 && a <= 5 && bb >= 1 && bb <= 5) {   // f=2,3: 5x5
                    float w2 = filt_s[2*49 + a*7 + bb];
                    float w3 = filt_s[3*49 + a*7 + bb];
                    y4[2].x = fmaf(w2, xv.x, y4[2].x); y4[2].y = fmaf(w2, xv.y, y4[2].y);
                    y4[2].z = fmaf(w2, xv.z, y4[2].z); y4[2].w = fmaf(w2, xv.w, y4[2].w);
                    y4[3].x = fmaf(w3, xv.x, y4[3].x); y4[3].y = fmaf(w3, xv.y, y4[3].y);
                    y4[3].z = fmaf(w3, xv.z, y4[3].z); y4[3].w = fmaf(w3, xv.w, y4[3].w);
                }
                if (a >= 2 && a <= 4 && bb >= 2 && bb <= 4) {   // f=0,1: 3x3
                    float w0 = filt_s[0*49 + a*7 + bb];
                    float w1 = filt_s[1*49 + a*7 + bb];
                    y4[0].x = fmaf(w0, xv.x, y4[0].x); y4[0].y = fmaf(w0, xv.y, y4[0].y);
                    y4[0].z = fmaf(w0, xv.z, y4[0].z); y4[0].w = fmaf(w0, xv.w, y4[0].w);
                    y4[1].x = fmaf(w1, xv.x, y4[1].x); y4[1].y = fmaf(w1, xv.y, y4[1].y);
                    y4[1].z = fmaf(w1, xv.z, y4[1].z); y4[1].w = fmaf(w1, xv.w, y4[1].w);
                }
            }
        }
        float4 m5 = make_float4(-INFINITY,-INFINITY,-INFINITY,-INFINITY);
        #pragma unroll
        for (int dy = -2; dy <= 2; dy++) {
            #pragma unroll
            for (int dx2 = -2; dx2 <= 2; dx2++) {
                if ((unsigned)(gy+dy) < 256u && (unsigned)(gx+dx2) < 256u)
                    m5 = f4max(m5, *(const float4*)&xs[((py+3+dy)*14 + (px1+3+dx2))*20 + q4]);
            }
        }
        float4 xc = *(const float4*)&xs[((py+3)*14 + (px1+3))*20 + q4];
        *(float4*)&perc[p*PST + q4] = xc;
        const int offY[6] = {16, 36, 52, 72, 88, 108};
        #pragma unroll
        for (int f = 0; f < 6; f++)
            *(float4*)&perc[p*PST + offY[f] + q4] = y4[f];
        *(float4*)&perc[p*PST + 124 + q4] = m5;

        if (q == 0) {
            float pre = -INFINITY;
            #pragma unroll
            for (int dy = -1; dy <= 1; dy++) {
                #pragma unroll
                for (int dx2 = -1; dx2 <= 1; dx2++) {
                    if ((unsigned)(gy+dy) < 256u && (unsigned)(gx+dx2) < 256u)
                        pre = fmaxf(pre, xs[((py+3+dy)*14 + (px1+3+dx2))*20 + 3]);
                }
            }
            prelife_out[(b << 16) + (gy << 8) + gx] = (pre > 0.1f) ? 1 : 0;
        }
    }
    __syncthreads();   // xs reads done; perc published. xs region -> w0sA.

    // ---- phase 2: MLP, double-buffered w0s ----
    const int kq   = t & 3;
    const int jg   = (t >> 2) & 3;
    const int quad = t >> 4;
    const int jg8  = jg << 3;
    const int p0px = quad << 2;

    const float* pp0 = &perc[(p0px    ) * PST + kq*36];
    const float* pp1 = &perc[(p0px + 1) * PST + kq*36];
    const float* pp2 = &perc[(p0px + 2) * PST + kq*36];
    const float* pp3 = &perc[(p0px + 3) * PST + kq*36];

    float dx[4][4];
    #pragma unroll
    for (int i = 0; i < 4; i++)
        #pragma unroll
        for (int c = 0; c < 4; c++) dx[i][c] = 0.f;

    *(float4*)&w0sA[wbase      ] = st0;
    *(float4*)&w0sA[wbase +  36] = st1;
    *(float4*)&w0sA[wbase +  72] = st2;
    *(float4*)&w0sA[wbase + 108] = st3;
    st0 = *(const float4*)(pW + 32);
    st1 = *(const float4*)(pW + 32 +  8192);
    st2 = *(const float4*)(pW + 32 + 16384);
    st3 = *(const float4*)(pW + 32 + 24576);
    __syncthreads();

    #pragma unroll 1
    for (int jc = 0; jc < 8; jc++) {
        const float* wrd = (jc & 1) ? w0sB : w0sA;
        float*       wwr = (jc & 1) ? w0sA : w0sB;

        float h[4][8];
        #pragma unroll
        for (int i = 0; i < 4; i++)
            #pragma unroll
            for (int jj = 0; jj < 8; jj++) h[i][jj] = 0.f;

        #pragma unroll
        for (int k4 = 0; k4 < 32; k4 += 4) {
            float4 pA0 = *(const float4*)&pp0[k4];
            float4 pA1 = *(const float4*)&pp1[k4];
            float4 pA2 = *(const float4*)&pp2[k4];
            float4 pA3 = *(const float4*)&pp3[k4];
            #pragma unroll
            for (int kk = 0; kk < 4; kk++) {
                float a0 = kk==0?pA0.x : kk==1?pA0.y : kk==2?pA0.z : pA0.w;
                float a1 = kk==0?pA1.x : kk==1?pA1.y : kk==2?pA1.z : pA1.w;
                float a2 = kk==0?pA2.x : kk==1?pA2.y : kk==2?pA2.z : pA2.w;
                float a3 = kk==0?pA3.x : kk==1?pA3.y : kk==2?pA3.z : pA3.w;
                const float* wr = &wrd[((k4 + kk)*4 + kq)*36 + jg8];
                float4 wA = *(const float4*)wr;
                float4 wB = *(const float4*)(wr + 4);
                #pragma unroll
                for (int i = 0; i < 4; i++) {
                    float ai = i==0?a0 : i==1?a1 : i==2?a2 : a3;
                    h[i][0] = fmaf(ai, wA.x, h[i][0]);
                    h[i][1] = fmaf(ai, wA.y, h[i][1]);
                    h[i][2] = fmaf(ai, wA.z, h[i][2]);
                    h[i][3] = fmaf(ai, wA.w, h[i][3]);
                    h[i][4] = fmaf(ai, wB.x, h[i][4]);
                    h[i][5] = fmaf(ai, wB.y, h[i][5]);
                    h[i][6] = fmaf(ai, wB.z, h[i][6]);
                    h[i][7] = fmaf(ai, wB.w, h[i][7]);
                }
            }
        }
        #pragma unroll
        for (int i = 0; i < 4; i++)
            #pragma unroll
            for (int jj = 0; jj < 8; jj++) {
                h[i][jj] += dpp_xor1(h[i][jj]);
                h[i][jj] += dpp_xor2(h[i][jj]);
            }
        const int jbase = (jc << 5) + jg8;
        float4 bA = *(const float4*)&b0[jbase];
        float4 bB = *(const float4*)&b0[jbase + 4];
        #pragma unroll
        for (int i = 0; i < 4; i++) {
            h[i][0] = fmaxf(h[i][0] + bA.x, 0.f);
            h[i][1] = fmaxf(h[i][1] + bA.y, 0.f);
            h[i][2] = fmaxf(h[i][2] + bA.z, 0.f);
            h[i][3] = fmaxf(h[i][3] + bA.w, 0.f);
            h[i][4] = fmaxf(h[i][4] + bB.x, 0.f);
            h[i][5] = fmaxf(h[i][5] + bB.y, 0.f);
            h[i][6] = fmaxf(h[i][6] + bB.z, 0.f);
            h[i][7] = fmaxf(h[i][7] + bB.w, 0.f);
        }
        #pragma unroll
        for (int jj = 0; jj < 8; jj++) {
            float4 wv = *(const float4*)&W1[((jbase + jj) << 4) + (kq << 2)];
            #pragma unroll
            for (int i = 0; i < 4; i++) {
                dx[i][0] = fmaf(h[i][jj], wv.x, dx[i][0]);
                dx[i][1] = fmaf(h[i][jj], wv.y, dx[i][1]);
                dx[i][2] = fmaf(h[i][jj], wv.z, dx[i][2]);
                dx[i][3] = fmaf(h[i][jj], wv.w, dx[i][3]);
            }
        }

        if (jc < 7) {
            *(float4*)&wwr[wbase      ] = st0;
            *(float4*)&wwr[wbase +  36] = st1;
            *(float4*)&wwr[wbase +  72] = st2;
            *(float4*)&wwr[wbase + 108] = st3;
            if (jc < 6) {
                const float* pN = pW + ((jc + 2) << 5);
                st0 = *(const float4*)(pN);
                st1 = *(const float4*)(pN +  8192);
                st2 = *(const float4*)(pN + 16384);
                st3 = *(const float4*)(pN + 24576);
            }
            __syncthreads();
        }
    }

    #pragma unroll
    for (int i = 0; i < 4; i++)
        #pragma unroll
        for (int c = 0; c < 4; c++) {
            dx[i][c] += __shfl_xor(dx[i][c], 4);
            dx[i][c] += __shfl_xor(dx[i][c], 8);
        }

    float o0 = jg==0?dx[0][0] : jg==1?dx[1][0] : jg==2?dx[2][0] : dx[3][0];
    float o1 = jg==0?dx[0][1] : jg==1?dx[1][1] : jg==2?dx[2][1] : dx[3][1];
    float o2 = jg==0?dx[0][2] : jg==1?dx[1][2] : jg==2?dx[2][2] : dx[3][2];
    float o3 = jg==0?dx[0][3] : jg==1?dx[1][3] : jg==2?dx[2][3] : dx[3][3];

    const int pw  = p0px + jg;
    const int ppy = pw >> 3, ppx = pw & 7;
    const int pix2 = (b << 16) + ((ty0 + ppy) << 8) + (tx0 + ppx);
    float fire = (stoch_s[pix2] > 0.5f) ? 1.f : 0.f;
    float4 xc2 = *(const float4*)&perc[pw*PST + (kq << 2)];
    float4 xn;
    xn.x = fmaf(fire, o0, xc2.x);
    xn.y = fmaf(fire, o1, xc2.y);
    xn.z = fmaf(fire, o2, xc2.z);
    xn.w = fmaf(fire, o3, xc2.w);
    *(float4*)&xmid[((size_t)pix2 << 4) + (kq << 2)] = xn;
}

// Final life masking (after step 16): alpha read from xbuf channel 3.
__global__ void step_mask(float* __restrict__ xbuf,
                          const unsigned char* __restrict__ prelife,
                          const float* __restrict__ valid) {
    int pix = blockIdx.x * 256 + threadIdx.x;
    int b = pix >> 16;
    int y = (pix >> 8) & 255;
    int x = pix & 255;
    float m = -INFINITY;
    #pragma unroll
    for (int dy = -1; dy <= 1; dy++) {
        #pragma unroll
        for (int dxo = -1; dxo <= 1; dxo++) {
            int yy = y + dy, xx = x + dxo;
            if ((unsigned)yy < 256u && (unsigned)xx < 256u)
                m = fmaxf(m, xbuf[((size_t)((b << 16) + (yy << 8) + xx) << 4) + 3]);
        }
    }
    float s = (prelife[pix] != 0 && m > 0.1f) ? valid[pix] : 0.f;
    float4* xp = (float4*)&xbuf[(size_t)pix << 4];
    #pragma unroll
    for (int i = 0; i < 4; i++) {
        float4 v = xp[i];
        v.x *= s; v.y *= s; v.z *= s; v.w *= s;
        xp[i] = v;
    }
}

extern "C" void kernel_launch(void* const* d_in, const int* in_sizes, int n_in,
                              void* d_out, int out_size, void* d_ws, size_t ws_size,
                              hipStream_t stream) {
    const float* x0    = (const float*)d_in[0];
    const float* valid = (const float*)d_in[1];
    const float* stoch = (const float*)d_in[2];
    const float* W0    = (const float*)d_in[3];
    const float* b0    = (const float*)d_in[4];
    const float* W1    = (const float*)d_in[5];

    float* ws   = (float*)d_ws;
    float* xA   = ws;                                    // 8388608 floats
    unsigned char* plA = (unsigned char*)(ws + 8388608); // 524288 B
    unsigned char* plB = plA + 524288;                   // 524288 B
    float* filt = ws + 8388608 + 262144;                 // after 1MB uchar
    float* out  = (float*)d_out;

    init_kernel<<<1, 64, 0, stream>>>(W0, filt);

    const float* src = x0;
    for (int k = 1; k <= 16; k++) {
        float* dst = (k & 1) ? xA : out;          // step 16 lands in d_out
        unsigned char* wr = (k & 1) ? plB : plA;  // step k writes this plane
        unsigned char* rd = (k & 1) ? plA : plB;  // reads prev step's plane
        step_main<<<dim3(32,32,8), 256, 0, stream>>>(
            src, dst, rd, wr, filt, W0, b0, W1,
            stoch + (size_t)(k-1)*NPIX, valid, (k > 1) ? 1 : 0);
        src = dst;
    }
    // step 16 (even k) wrote plane plA; final mask on d_out
    step_mask<<<NPIX/256, 256, 0, stream>>>(out, plA, valid);
}

// Round 20
// 11229.939 us; speedup vs baseline: 3.9646x; 1.2216x over previous
//
#include <hip/hip_runtime.h>
#include <math.h>

// NCA: B=8, H=W=256, C=16, 16 steps.
// R20: GEMM1 via split-bf16 MFMA (bf16x3: ahi*bhi + ahi*blo + alo*bhi, fp32
// acc) on v_mfma_f32_16x16x32_bf16. perc stored as bf16 hi/lo [64][136];
// W0 pre-split+pre-transposed in init (W0hiT/loT [256j][128k]). Wave=m-tile,
// C layout per m89 (col=lane&15, row=4(lane>>4)+reg); A/B use matching
// contiguous k-blocks (k-permutation cancels when A,B agree). h->LDS hbuf,
// then R19's scalar GEMM2 + jg-shfl reduce + fused-mask epilogue unchanged.
// Error budget: ~1e-4 rel on h -> ~3e-3 final after x200-500 amplification;
// + fp32 baseline 0.0156 => predicted absmax 0.02-0.05 < 0.07.

#define HW 256
#define NPIX (8*HW*HW)   // 524288

typedef __attribute__((ext_vector_type(8))) short short8;
typedef __attribute__((ext_vector_type(4))) float f32x4;

__device__ __forceinline__ float4 f4max(float4 a, float4 b) {
    return make_float4(fmaxf(a.x,b.x), fmaxf(a.y,b.y), fmaxf(a.z,b.z), fmaxf(a.w,b.w));
}
__device__ __forceinline__ unsigned short bf16_rne(float v) {
    unsigned int u = __float_as_uint(v);
    unsigned int r = u + 0x7FFFu + ((u >> 16) & 1u);
    return (unsigned short)(r >> 16);
}
__device__ __forceinline__ float bf16f(unsigned short h) {
    return __uint_as_float(((unsigned int)h) << 16);
}

// Sobel bank + W0 split/transpose: W0hiT/W0loT[j][k] bf16.
__global__ void init_kernel(const float* __restrict__ W0,
                            float* __restrict__ filt,
                            unsigned short* __restrict__ W0hiT,
                            unsigned short* __restrict__ W0loT) {
    int t = blockIdx.x * blockDim.x + threadIdx.x;
    for (int idx = t; idx < 32768; idx += gridDim.x * blockDim.x) {
        int j = idx >> 7, k = idx & 127;
        float v = W0[k * 256 + j];
        unsigned short hi = bf16_rne(v);
        unsigned short lo = bf16_rne(v - bf16f(hi));
        W0hiT[idx] = hi;
        W0loT[idx] = lo;
    }
    if (t < 6) {
        int f = t;
        int size = 3 + 2*(f >> 1);
        int p0 = (7 - size) >> 1;
        int isY = f & 1;
        float vals[49];
        float norm = 0.f;
        for (int a = 0; a < 7; a++) {
            for (int b = 0; b < 7; b++) {
                float v = 0.f;
                if (a >= p0 && a < p0+size && b >= p0 && b < p0+size) {
                    float fy = (float)(a - 3), fx = (float)(b - 3);
                    float den = fx*fx + fy*fy;
                    if (den == 0.f) den = 1.f;
                    v = (isY ? fy : fx) / den;
                }
                vals[a*7+b] = v;
                norm += fabsf(v);
            }
        }
        float inv = 1.f / norm;
        for (int i = 0; i < 49; i++) filt[f*49 + i] = vals[i] * inv;
    }
}

__launch_bounds__(256, 2)
__global__ void step_main(const float* __restrict__ x,
                          float* __restrict__ xmid,
                          const unsigned char* __restrict__ prelife_in,
                          unsigned char* __restrict__ prelife_out,
                          const float* __restrict__ filt_g,
                          const unsigned short* __restrict__ W0hiT,
                          const unsigned short* __restrict__ W0loT,
                          const float* __restrict__ b0,
                          const float* __restrict__ W1,
                          const float* __restrict__ stoch_s,
                          const float* __restrict__ valid,
                          int apply_mask) {
    // floats: [0,4352) w0h|w0l (phase2) ALIAS xs 3920 + filt 294 (phase1)
    //         [4352,8704) perc_hi bf16[64][136]  [8704,13056) perc_lo
    //         [13056,15360) hbuf fp32[64][36]    [15360,16640) xcen[64][20]
    __shared__ float smem[16640];
    float*          xs      = smem;                 // phase 1
    float*          filt_s  = smem + 3920;          // phase 1
    unsigned short* w0h     = (unsigned short*)smem;            // phase 2
    unsigned short* w0l     = (unsigned short*)(smem + 2176);   // phase 2
    unsigned short* perc_hi = (unsigned short*)(smem + 4352);
    unsigned short* perc_lo = (unsigned short*)(smem + 8704);
    float*          hbuf    = smem + 13056;
    float*          xcen    = smem + 15360;

    const int t   = threadIdx.x;
    const int b   = blockIdx.z;
    const int ty0 = blockIdx.y * 8;
    const int tx0 = blockIdx.x * 8;

    // staging geometry: thread t stages row j'=t>>3 (of 32), 16 k at (t&7)*16
    const int sgbase = ((t >> 3) << 7) + ((t & 7) << 4);   // within chunk
    const int swds   = (t >> 3) * 136 + ((t & 7) << 4);    // LDS dest
    // prefetch chunk 0
    uint4 sh0 = *(const uint4*)&W0hiT[sgbase];
    uint4 sh1 = *(const uint4*)&W0hiT[sgbase + 8];
    uint4 sl0 = *(const uint4*)&W0loT[sgbase];
    uint4 sl1 = *(const uint4*)&W0loT[sgbase + 8];

    for (int i = t; i < 294; i += 256) filt_s[i] = filt_g[i];

    // stage x tile + halo with FUSED life-mask (R19)
    if (t < 196) {
        const int ly = t / 14, lx = t - ly*14;
        const int gy = ty0 + ly - 3, gx = tx0 + lx - 3;
        const bool inb = ((unsigned)gy < 256u) && ((unsigned)gx < 256u);
        float4 v0 = make_float4(0.f,0.f,0.f,0.f), v1 = v0, v2 = v0, v3 = v0;
        if (inb) {
            const int pix = (b << 16) + (gy << 8) + gx;
            const float* srcp = &x[(size_t)pix << 4];
            v0 = *(const float4*)(srcp);
            v1 = *(const float4*)(srcp + 4);
            v2 = *(const float4*)(srcp + 8);
            v3 = *(const float4*)(srcp + 12);
            if (apply_mask) {
                float m = -INFINITY;
                #pragma unroll
                for (int dy = -1; dy <= 1; dy++) {
                    #pragma unroll
                    for (int dxo = -1; dxo <= 1; dxo++) {
                        int yy = gy + dy, xx2 = gx + dxo;
                        if ((unsigned)yy < 256u && (unsigned)xx2 < 256u)
                            m = fmaxf(m, x[((size_t)((b<<16)+(yy<<8)+xx2) << 4) + 3]);
                    }
                }
                float s = (prelife_in[pix] != 0 && m > 0.1f) ? valid[pix] : 0.f;
                v0.x *= s; v0.y *= s; v0.z *= s; v0.w *= s;
                v1.x *= s; v1.y *= s; v1.z *= s; v1.w *= s;
                v2.x *= s; v2.y *= s; v2.z *= s; v2.w *= s;
                v3.x *= s; v3.y *= s; v3.z *= s; v3.w *= s;
            }
        }
        float* dstp = &xs[t * 20];
        *(float4*)(dstp)      = v0;
        *(float4*)(dstp + 4)  = v1;
        *(float4*)(dstp + 8)  = v2;
        *(float4*)(dstp + 12) = v3;
    }
    __syncthreads();

    {   // ---- phase 1: sparse conv + pools -> perc (bf16 hi/lo) + xcen ----
        const int p  = t & 63;
        const int q  = t >> 6;
        const int py = p >> 3, px1 = p & 7;
        const int gy = ty0 + py, gx = tx0 + px1;
        const int q4 = q << 2;

        float4 y4[6];
        #pragma unroll
        for (int f = 0; f < 6; f++) y4[f] = make_float4(0.f,0.f,0.f,0.f);

        #pragma unroll
        for (int a = 0; a < 7; a++) {
            #pragma unroll
            for (int bb = 0; bb < 7; bb++) {
                float4 xv = *(const float4*)&xs[((py+a)*14 + (px1+bb))*20 + q4];
                {   // f=4,5: full 7x7
                    float w4 = filt_s[4*49 + a*7 + bb];
                    float w5 = filt_s[5*49 + a*7 + bb];
                    y4[4].x = fmaf(w4, xv.x, y4[4].x); y4[4].y = fmaf(w4, xv.y, y4[4].y);
                    y4[4].z = fmaf(w4, xv.z, y4[4].z); y4[4].w = fmaf(w4, xv.w, y4[4].w);
                    y4[5].x = fmaf(w5, xv.x, y4[5].x); y4[5].y = fmaf(w5, xv.y, y4[5].y);
                    y4[5].z = fmaf(w5, xv.z, y4[5].z); y4[5].w = fmaf(w5, xv.w, y4[5].w);
                }
                if (a >= 1 && a <= 5 && bb >= 1 && bb <= 5) {   // f=2,3: 5x5
                    float w2 = filt_s[2*49 + a*7 + bb];
                    float w3 = filt_s[3*49 + a*7 + bb];
                    y4[2].x = fmaf(w2, xv.x, y4[2].x); y4[2].y = fmaf(w2, xv.y, y4[2].y);
                    y4[2].z = fmaf(w2, xv.z, y4[2].z); y4[2].w = fmaf(w2, xv.w, y4[2].w);
                    y4[3].x = fmaf(w3, xv.x, y4[3].x); y4[3].y = fmaf(w3, xv.y, y4[3].y);
                    y4[3].z = fmaf(w3, xv.z, y4[3].z); y4[3].w = fmaf(w3, xv.w, y4[3].w);
                }
                if (a >= 2 && a <= 4 && bb >= 2 && bb <= 4) {   // f=0,1: 3x3
                    float w0 = filt_s[0*49 + a*7 + bb];
                    float w1 = filt_s[1*49 + a*7 + bb];
                    y4[0].x = fmaf(w0, xv.x, y4[0].x); y4[0].y = fmaf(w0, xv.y, y4[0].y);
                    y4[0].z = fmaf(w0, xv.z, y4[0].z); y4[0].w = fmaf(w0, xv.w, y4[0].w);
                    y4[1].x = fmaf(w1, xv.x, y4[1].x); y4[1].y = fmaf(w1, xv.y, y4[1].y);
                    y4[1].z = fmaf(w1, xv.z, y4[1].z); y4[1].w = fmaf(w1, xv.w, y4[1].w);
                }
            }
        }
        float4 m5 = make_float4(-INFINITY,-INFINITY,-INFINITY,-INFINITY);
        #pragma unroll
        for (int dy = -2; dy <= 2; dy++) {
            #pragma unroll
            for (int dx2 = -2; dx2 <= 2; dx2++) {
                if ((unsigned)(gy+dy) < 256u && (unsigned)(gx+dx2) < 256u)
                    m5 = f4max(m5, *(const float4*)&xs[((py+3+dy)*14 + (px1+3+dx2))*20 + q4]);
            }
        }
        float4 xc = *(const float4*)&xs[((py+3)*14 + (px1+3))*20 + q4];

        // split-store helper (hi/lo bf16, 8B each)
        #define SPLIT4(arridx, v) { \
            unsigned short h0 = bf16_rne((v).x), h1 = bf16_rne((v).y); \
            unsigned short h2 = bf16_rne((v).z), h3 = bf16_rne((v).w); \
            unsigned short l0 = bf16_rne((v).x - bf16f(h0)); \
            unsigned short l1 = bf16_rne((v).y - bf16f(h1)); \
            unsigned short l2 = bf16_rne((v).z - bf16f(h2)); \
            unsigned short l3 = bf16_rne((v).w - bf16f(h3)); \
            *(ushort4*)&perc_hi[arridx] = make_ushort4(h0,h1,h2,h3); \
            *(ushort4*)&perc_lo[arridx] = make_ushort4(l0,l1,l2,l3); }

        const int prow = p * 136;
        SPLIT4(prow +       q4, xc);      // k 0-15: x
        SPLIT4(prow + 16  + q4, y4[0]);   // k 16+16f: y_f (f-major)
        SPLIT4(prow + 32  + q4, y4[1]);
        SPLIT4(prow + 48  + q4, y4[2]);
        SPLIT4(prow + 64  + q4, y4[3]);
        SPLIT4(prow + 80  + q4, y4[4]);
        SPLIT4(prow + 96  + q4, y4[5]);
        SPLIT4(prow + 112 + q4, m5);      // k 112-127: pool5
        #undef SPLIT4

        *(float4*)&xcen[p*20 + q4] = xc;  // masked center for epilogue

        if (q == 0) {
            float pre = -INFINITY;
            #pragma unroll
            for (int dy = -1; dy <= 1; dy++) {
                #pragma unroll
                for (int dx2 = -1; dx2 <= 1; dx2++) {
                    if ((unsigned)(gy+dy) < 256u && (unsigned)(gx+dx2) < 256u)
                        pre = fmaxf(pre, xs[((py+3+dy)*14 + (px1+3+dx2))*20 + 3]);
                }
            }
            prelife_out[(b << 16) + (gy << 8) + gx] = (pre > 0.1f) ? 1 : 0;
        }
    }
    __syncthreads();   // xs reads done; perc published. xs region -> w0h/w0l.

    // ---- phase 2: MFMA GEMM1 (bf16x3) + scalar GEMM2 ----
    const int lane = t & 63;
    const int wid  = t >> 6;        // m-tile (16 px)
    const int l15  = lane & 15;
    const int l4   = lane >> 4;     // 0..3
    const int aoff = (wid*16 + l15)*136 + 8*l4;   // A frag base (+ks*32)
    const int boff0 = (l15)*136 + 8*l4;           // B frag, nt=0
    const int boff1 = (16 + l15)*136 + 8*l4;      // B frag, nt=1
    const int hrow  = wid*16 + 4*l4;              // hbuf row (+r)

    // GEMM2 roles (kq = channel quad now; no k-split)
    const int kq   = t & 3;
    const int jg   = (t >> 2) & 3;
    const int quad = t >> 4;
    const int jg8  = jg << 3;
    const int p0px = quad << 2;

    float dx[4][4];
    #pragma unroll
    for (int i = 0; i < 4; i++)
        #pragma unroll
        for (int c = 0; c < 4; c++) dx[i][c] = 0.f;

    // write chunk 0; prefetch chunk 1
    *(uint4*)&w0h[swds]     = sh0;
    *(uint4*)&w0h[swds + 8] = sh1;
    *(uint4*)&w0l[swds]     = sl0;
    *(uint4*)&w0l[swds + 8] = sl1;
    sh0 = *(const uint4*)&W0hiT[sgbase + 4096];
    sh1 = *(const uint4*)&W0hiT[sgbase + 4096 + 8];
    sl0 = *(const uint4*)&W0loT[sgbase + 4096];
    sl1 = *(const uint4*)&W0loT[sgbase + 4096 + 8];
    __syncthreads();   // w0(0) visible

    #pragma unroll 1
    for (int jc = 0; jc < 8; jc++) {
        // ---- GEMM1 via MFMA: 64px x 32j x 128k, bf16x3 ----
        short8 ah0 = *(const short8*)&perc_hi[aoff +  0];
        short8 ah1 = *(const short8*)&perc_hi[aoff + 32];
        short8 ah2 = *(const short8*)&perc_hi[aoff + 64];
        short8 ah3 = *(const short8*)&perc_hi[aoff + 96];
        short8 al0 = *(const short8*)&perc_lo[aoff +  0];
        short8 al1 = *(const short8*)&perc_lo[aoff + 32];
        short8 al2 = *(const short8*)&perc_lo[aoff + 64];
        short8 al3 = *(const short8*)&perc_lo[aoff + 96];

        f32x4 acc0 = {0.f, 0.f, 0.f, 0.f};
        f32x4 acc1 = {0.f, 0.f, 0.f, 0.f};

        #define KSTEP(accv, boff, AH, AL, ks) { \
            short8 bh = *(const short8*)&w0h[(boff) + (ks)*32]; \
            short8 bl = *(const short8*)&w0l[(boff) + (ks)*32]; \
            accv = __builtin_amdgcn_mfma_f32_16x16x32_bf16(AL, bh, accv, 0, 0, 0); \
            accv = __builtin_amdgcn_mfma_f32_16x16x32_bf16(AH, bl, accv, 0, 0, 0); \
            accv = __builtin_amdgcn_mfma_f32_16x16x32_bf16(AH, bh, accv, 0, 0, 0); }

        KSTEP(acc0, boff0, ah0, al0, 0)
        KSTEP(acc0, boff0, ah1, al1, 1)
        KSTEP(acc0, boff0, ah2, al2, 2)
        KSTEP(acc0, boff0, ah3, al3, 3)
        KSTEP(acc1, boff1, ah0, al0, 0)
        KSTEP(acc1, boff1, ah1, al1, 1)
        KSTEP(acc1, boff1, ah2, al2, 2)
        KSTEP(acc1, boff1, ah3, al3, 3)
        #undef KSTEP

        // bias + relu, write h to hbuf (C layout: col=l15, row=4*l4+r)
        {
            float bias0 = b0[jc*32 + l15];
            float bias1 = b0[jc*32 + 16 + l15];
            hbuf[(hrow+0)*36 + l15]      = fmaxf(acc0[0] + bias0, 0.f);
            hbuf[(hrow+1)*36 + l15]      = fmaxf(acc0[1] + bias0, 0.f);
            hbuf[(hrow+2)*36 + l15]      = fmaxf(acc0[2] + bias0, 0.f);
            hbuf[(hrow+3)*36 + l15]      = fmaxf(acc0[3] + bias0, 0.f);
            hbuf[(hrow+0)*36 + 16 + l15] = fmaxf(acc1[0] + bias1, 0.f);
            hbuf[(hrow+1)*36 + 16 + l15] = fmaxf(acc1[1] + bias1, 0.f);
            hbuf[(hrow+2)*36 + 16 + l15] = fmaxf(acc1[2] + bias1, 0.f);
            hbuf[(hrow+3)*36 + 16 + l15] = fmaxf(acc1[3] + bias1, 0.f);
        }
        __syncthreads();   // hbuf visible; all w0(jc) reads done

        if (jc < 7) {      // safe: MFMA reads of w0 complete
            *(uint4*)&w0h[swds]     = sh0;
            *(uint4*)&w0h[swds + 8] = sh1;
            *(uint4*)&w0l[swds]     = sl0;
            *(uint4*)&w0l[swds + 8] = sl1;
        }

        // ---- GEMM2: dx[4px][4ch] += h * W1 (scalar, as R19) ----
        const int jbase = (jc << 5) + jg8;
        #pragma unroll
        for (int i = 0; i < 4; i++) {
            const float* hp = &hbuf[(p0px + i)*36 + jg8];
            float4 hA = *(const float4*)hp;
            float4 hB = *(const float4*)(hp + 4);
            #pragma unroll
            for (int jj = 0; jj < 8; jj++) {
                float hv = jj==0?hA.x : jj==1?hA.y : jj==2?hA.z : jj==3?hA.w :
                           jj==4?hB.x : jj==5?hB.y : jj==6?hB.z : hB.w;
                float4 wv = *(const float4*)&W1[((jbase + jj) << 4) + (kq << 2)];
                dx[i][0] = fmaf(hv, wv.x, dx[i][0]);
                dx[i][1] = fmaf(hv, wv.y, dx[i][1]);
                dx[i][2] = fmaf(hv, wv.z, dx[i][2]);
                dx[i][3] = fmaf(hv, wv.w, dx[i][3]);
            }
        }

        if (jc < 7) {
            __syncthreads();   // w0(jc+1) visible; hbuf reads done
            if (jc < 6) {
                const int nb = sgbase + (jc + 2) * 4096;
                sh0 = *(const uint4*)&W0hiT[nb];
                sh1 = *(const uint4*)&W0hiT[nb + 8];
                sl0 = *(const uint4*)&W0loT[nb];
                sl1 = *(const uint4*)&W0loT[nb + 8];
            }
        }
    }

    // reduce dx over the 4 jg lanes (bits 2-3)
    #pragma unroll
    for (int i = 0; i < 4; i++)
        #pragma unroll
        for (int c = 0; c < 4; c++) {
            dx[i][c] += __shfl_xor(dx[i][c], 4);
            dx[i][c] += __shfl_xor(dx[i][c], 8);
        }

    // writer: pixel 4quad+jg, channels kq*4..+4
    float o0 = jg==0?dx[0][0] : jg==1?dx[1][0] : jg==2?dx[2][0] : dx[3][0];
    float o1 = jg==0?dx[0][1] : jg==1?dx[1][1] : jg==2?dx[2][1] : dx[3][1];
    float o2 = jg==0?dx[0][2] : jg==1?dx[1][2] : jg==2?dx[2][2] : dx[3][2];
    float o3 = jg==0?dx[0][3] : jg==1?dx[1][3] : jg==2?dx[2][3] : dx[3][3];

    const int pw  = p0px + jg;
    const int ppy = pw >> 3, ppx = pw & 7;
    const int pix2 = (b << 16) + ((ty0 + ppy) << 8) + (tx0 + ppx);
    float fire = (stoch_s[pix2] > 0.5f) ? 1.f : 0.f;
    float4 xc2 = *(const float4*)&xcen[pw*20 + (kq << 2)];
    float4 xn;
    xn.x = fmaf(fire, o0, xc2.x);
    xn.y = fmaf(fire, o1, xc2.y);
    xn.z = fmaf(fire, o2, xc2.z);
    xn.w = fmaf(fire, o3, xc2.w);
    *(float4*)&xmid[((size_t)pix2 << 4) + (kq << 2)] = xn;
}

// Final life masking (after step 16): alpha read from xbuf channel 3.
__global__ void step_mask(float* __restrict__ xbuf,
                          const unsigned char* __restrict__ prelife,
                          const float* __restrict__ valid) {
    int pix = blockIdx.x * 256 + threadIdx.x;
    int b = pix >> 16;
    int y = (pix >> 8) & 255;
    int x = pix & 255;
    float m = -INFINITY;
    #pragma unroll
    for (int dy = -1; dy <= 1; dy++) {
        #pragma unroll
        for (int dxo = -1; dxo <= 1; dxo++) {
            int yy = y + dy, xx = x + dxo;
            if ((unsigned)yy < 256u && (unsigned)xx < 256u)
                m = fmaxf(m, xbuf[((size_t)((b << 16) + (yy << 8) + xx) << 4) + 3]);
        }
    }
    float s = (prelife[pix] != 0 && m > 0.1f) ? valid[pix] : 0.f;
    float4* xp = (float4*)&xbuf[(size_t)pix << 4];
    #pragma unroll
    for (int i = 0; i < 4; i++) {
        float4 v = xp[i];
        v.x *= s; v.y *= s; v.z *= s; v.w *= s;
        xp[i] = v;
    }
}

extern "C" void kernel_launch(void* const* d_in, const int* in_sizes, int n_in,
                              void* d_out, int out_size, void* d_ws, size_t ws_size,
                              hipStream_t stream) {
    const float* x0    = (const float*)d_in[0];
    const float* valid = (const float*)d_in[1];
    const float* stoch = (const float*)d_in[2];
    const float* W0    = (const float*)d_in[3];
    const float* b0    = (const float*)d_in[4];
    const float* W1    = (const float*)d_in[5];

    float* ws   = (float*)d_ws;
    float* xA   = ws;                                    // [0, 8388608)
    unsigned char* plA = (unsigned char*)(ws + 8388608); // 512KB
    unsigned char* plB = plA + 524288;                   // 512KB
    float* filt = ws + 8650752;                          // 320
    unsigned short* W0hiT = (unsigned short*)(ws + 8651072);  // 32768 us
    unsigned short* W0loT = (unsigned short*)(ws + 8667456);  // 32768 us
    float* out  = (float*)d_out;

    init_kernel<<<128, 256, 0, stream>>>(W0, filt, W0hiT, W0loT);

    const float* src = x0;
    for (int k = 1; k <= 16; k++) {
        float* dst = (k & 1) ? xA : out;          // step 16 lands in d_out
        unsigned char* wr = (k & 1) ? plB : plA;
        unsigned char* rd = (k & 1) ? plA : plB;
        step_main<<<dim3(32,32,8), 256, 0, stream>>>(
            src, dst, rd, wr, filt, W0hiT, W0loT, b0, W1,
            stoch + (size_t)(k-1)*NPIX, valid, (k > 1) ? 1 : 0);
        src = dst;
    }
    step_mask<<<NPIX/256, 256, 0, stream>>>(out, plA, valid);
}

// Round 21
// 10593.790 us; speedup vs baseline: 4.2027x; 1.0600x over previous
//
#include <hip/hip_runtime.h>
#include <math.h>

// NCA: B=8, H=W=256, C=16, 16 steps.
// R21: both GEMMs on MFMA (split-bf16). GEMM2: h->hbuf (bf16 hi/lo, WAVE-
// LOCAL -> no barrier), B = W1T2[ch][j] bf16 frags (global, L1-hot),
// dacc accumulated across chunks in MFMA C regs. w0 double-buffered ->
// 1 barrier/chunk (11 total, was 19). GEMM1 A-frags hoisted (loop-inv).
// xcen deleted: epilogue reconstructs masked x from perc hi+lo (err 2^-17).
// LDS 78.8KB -> 2 blocks/CU. Epilogue: lane=(ch=l15, px=16wid+4*l4+r).

#define HW 256
#define NPIX (8*HW*HW)   // 524288

typedef __attribute__((ext_vector_type(8))) short short8;
typedef __attribute__((ext_vector_type(4))) float f32x4;

__device__ __forceinline__ float4 f4max(float4 a, float4 b) {
    return make_float4(fmaxf(a.x,b.x), fmaxf(a.y,b.y), fmaxf(a.z,b.z), fmaxf(a.w,b.w));
}
__device__ __forceinline__ unsigned short bf16_rne(float v) {
    unsigned int u = __float_as_uint(v);
    unsigned int r = u + 0x7FFFu + ((u >> 16) & 1u);
    return (unsigned short)(r >> 16);
}
__device__ __forceinline__ float bf16f(unsigned short h) {
    return __uint_as_float(((unsigned int)h) << 16);
}

// Sobel bank + W0 split/transpose [j][k] + W1 split/transpose [ch][j].
__global__ void init_kernel(const float* __restrict__ W0,
                            const float* __restrict__ W1,
                            float* __restrict__ filt,
                            unsigned short* __restrict__ W0hiT,
                            unsigned short* __restrict__ W0loT,
                            unsigned short* __restrict__ W1hiT2,
                            unsigned short* __restrict__ W1loT2) {
    int t = blockIdx.x * blockDim.x + threadIdx.x;
    int nth = gridDim.x * blockDim.x;
    for (int idx = t; idx < 32768; idx += nth) {
        int j = idx >> 7, k = idx & 127;
        float v = W0[k * 256 + j];
        unsigned short hi = bf16_rne(v);
        unsigned short lo = bf16_rne(v - bf16f(hi));
        W0hiT[idx] = hi;
        W0loT[idx] = lo;
    }
    for (int idx = t; idx < 4096; idx += nth) {
        int ch = idx >> 8, j = idx & 255;
        float v = W1[j * 16 + ch];
        unsigned short hi = bf16_rne(v);
        unsigned short lo = bf16_rne(v - bf16f(hi));
        W1hiT2[idx] = hi;
        W1loT2[idx] = lo;
    }
    if (t < 6) {
        int f = t;
        int size = 3 + 2*(f >> 1);
        int p0 = (7 - size) >> 1;
        int isY = f & 1;
        float vals[49];
        float norm = 0.f;
        for (int a = 0; a < 7; a++) {
            for (int b = 0; b < 7; b++) {
                float v = 0.f;
                if (a >= p0 && a < p0+size && b >= p0 && b < p0+size) {
                    float fy = (float)(a - 3), fx = (float)(b - 3);
                    float den = fx*fx + fy*fy;
                    if (den == 0.f) den = 1.f;
                    v = (isY ? fy : fx) / den;
                }
                vals[a*7+b] = v;
                norm += fabsf(v);
            }
        }
        float inv = 1.f / norm;
        for (int i = 0; i < 49; i++) filt[f*49 + i] = vals[i] * inv;
    }
}

__launch_bounds__(256, 2)
__global__ void step_main(const float* __restrict__ x,
                          float* __restrict__ xmid,
                          const unsigned char* __restrict__ prelife_in,
                          unsigned char* __restrict__ prelife_out,
                          const float* __restrict__ filt_g,
                          const unsigned short* __restrict__ W0hiT,
                          const unsigned short* __restrict__ W0loT,
                          const unsigned short* __restrict__ W1hiT2,
                          const unsigned short* __restrict__ W1loT2,
                          const float* __restrict__ b0,
                          const float* __restrict__ stoch_s,
                          const float* __restrict__ valid,
                          int apply_mask) {
    // floats: [0,8704) w0 dbuf (hA|lA|hB|lB, 2176 fl each) ALIAS phase1
    //         xs[0,3920)+filt[3920,4214)
    //         [8704,13056) perc_hi us[64][136]  [13056,17408) perc_lo
    //         [17408,18560) hbuf_hi us[64][36]  [18560,19712) hbuf_lo
    __shared__ float smem[19712];
    float*          xs      = smem;
    float*          filt_s  = smem + 3920;
    unsigned short* w0hA    = (unsigned short*)smem;
    unsigned short* w0lA    = (unsigned short*)(smem + 2176);
    unsigned short* w0hB    = (unsigned short*)(smem + 4352);
    unsigned short* w0lB    = (unsigned short*)(smem + 6528);
    unsigned short* perc_hi = (unsigned short*)(smem + 8704);
    unsigned short* perc_lo = (unsigned short*)(smem + 13056);
    unsigned short* hbuf_hi = (unsigned short*)(smem + 17408);
    unsigned short* hbuf_lo = (unsigned short*)(smem + 18560);

    const int t   = threadIdx.x;
    const int b   = blockIdx.z;
    const int ty0 = blockIdx.y * 8;
    const int tx0 = blockIdx.x * 8;

    // staging geometry (chunk = 32j x 128k): row j'=t>>3, 16 k at (t&7)*16
    const int sgbase = ((t >> 3) << 7) + ((t & 7) << 4);
    const int swds   = (t >> 3) * 136 + ((t & 7) << 4);
    uint4 sh0 = *(const uint4*)&W0hiT[sgbase];
    uint4 sh1 = *(const uint4*)&W0hiT[sgbase + 8];
    uint4 sl0 = *(const uint4*)&W0loT[sgbase];
    uint4 sl1 = *(const uint4*)&W0loT[sgbase + 8];

    for (int i = t; i < 294; i += 256) filt_s[i] = filt_g[i];

    // stage x tile + halo with FUSED life-mask
    if (t < 196) {
        const int ly = t / 14, lx = t - ly*14;
        const int gy = ty0 + ly - 3, gx = tx0 + lx - 3;
        const bool inb = ((unsigned)gy < 256u) && ((unsigned)gx < 256u);
        float4 v0 = make_float4(0.f,0.f,0.f,0.f), v1 = v0, v2 = v0, v3 = v0;
        if (inb) {
            const int pix = (b << 16) + (gy << 8) + gx;
            const float* srcp = &x[(size_t)pix << 4];
            v0 = *(const float4*)(srcp);
            v1 = *(const float4*)(srcp + 4);
            v2 = *(const float4*)(srcp + 8);
            v3 = *(const float4*)(srcp + 12);
            if (apply_mask) {
                float m = -INFINITY;
                #pragma unroll
                for (int dy = -1; dy <= 1; dy++) {
                    #pragma unroll
                    for (int dxo = -1; dxo <= 1; dxo++) {
                        int yy = gy + dy, xx2 = gx + dxo;
                        if ((unsigned)yy < 256u && (unsigned)xx2 < 256u)
                            m = fmaxf(m, x[((size_t)((b<<16)+(yy<<8)+xx2) << 4) + 3]);
                    }
                }
                float s = (prelife_in[pix] != 0 && m > 0.1f) ? valid[pix] : 0.f;
                v0.x *= s; v0.y *= s; v0.z *= s; v0.w *= s;
                v1.x *= s; v1.y *= s; v1.z *= s; v1.w *= s;
                v2.x *= s; v2.y *= s; v2.z *= s; v2.w *= s;
                v3.x *= s; v3.y *= s; v3.z *= s; v3.w *= s;
            }
        }
        float* dstp = &xs[t * 20];
        *(float4*)(dstp)      = v0;
        *(float4*)(dstp + 4)  = v1;
        *(float4*)(dstp + 8)  = v2;
        *(float4*)(dstp + 12) = v3;
    }
    __syncthreads();

    {   // ---- phase 1: sparse conv + pools -> perc (bf16 hi/lo) ----
        const int p  = t & 63;
        const int q  = t >> 6;
        const int py = p >> 3, px1 = p & 7;
        const int gy = ty0 + py, gx = tx0 + px1;
        const int q4 = q << 2;

        float4 y4[6];
        #pragma unroll
        for (int f = 0; f < 6; f++) y4[f] = make_float4(0.f,0.f,0.f,0.f);

        #pragma unroll
        for (int a = 0; a < 7; a++) {
            #pragma unroll
            for (int bb = 0; bb < 7; bb++) {
                float4 xv = *(const float4*)&xs[((py+a)*14 + (px1+bb))*20 + q4];
                {   // f=4,5: full 7x7
                    float w4 = filt_s[4*49 + a*7 + bb];
                    float w5 = filt_s[5*49 + a*7 + bb];
                    y4[4].x = fmaf(w4, xv.x, y4[4].x); y4[4].y = fmaf(w4, xv.y, y4[4].y);
                    y4[4].z = fmaf(w4, xv.z, y4[4].z); y4[4].w = fmaf(w4, xv.w, y4[4].w);
                    y4[5].x = fmaf(w5, xv.x, y4[5].x); y4[5].y = fmaf(w5, xv.y, y4[5].y);
                    y4[5].z = fmaf(w5, xv.z, y4[5].z); y4[5].w = fmaf(w5, xv.w, y4[5].w);
                }
                if (a >= 1 && a <= 5 && bb >= 1 && bb <= 5) {   // f=2,3: 5x5
                    float w2 = filt_s[2*49 + a*7 + bb];
                    float w3 = filt_s[3*49 + a*7 + bb];
                    y4[2].x = fmaf(w2, xv.x, y4[2].x); y4[2].y = fmaf(w2, xv.y, y4[2].y);
                    y4[2].z = fmaf(w2, xv.z, y4[2].z); y4[2].w = fmaf(w2, xv.w, y4[2].w);
                    y4[3].x = fmaf(w3, xv.x, y4[3].x); y4[3].y = fmaf(w3, xv.y, y4[3].y);
                    y4[3].z = fmaf(w3, xv.z, y4[3].z); y4[3].w = fmaf(w3, xv.w, y4[3].w);
                }
                if (a >= 2 && a <= 4 && bb >= 2 && bb <= 4) {   // f=0,1: 3x3
                    float w0 = filt_s[0*49 + a*7 + bb];
                    float w1 = filt_s[1*49 + a*7 + bb];
                    y4[0].x = fmaf(w0, xv.x, y4[0].x); y4[0].y = fmaf(w0, xv.y, y4[0].y);
                    y4[0].z = fmaf(w0, xv.z, y4[0].z); y4[0].w = fmaf(w0, xv.w, y4[0].w);
                    y4[1].x = fmaf(w1, xv.x, y4[1].x); y4[1].y = fmaf(w1, xv.y, y4[1].y);
                    y4[1].z = fmaf(w1, xv.z, y4[1].z); y4[1].w = fmaf(w1, xv.w, y4[1].w);
                }
            }
        }
        float4 m5 = make_float4(-INFINITY,-INFINITY,-INFINITY,-INFINITY);
        #pragma unroll
        for (int dy = -2; dy <= 2; dy++) {
            #pragma unroll
            for (int dx2 = -2; dx2 <= 2; dx2++) {
                if ((unsigned)(gy+dy) < 256u && (unsigned)(gx+dx2) < 256u)
                    m5 = f4max(m5, *(const float4*)&xs[((py+3+dy)*14 + (px1+3+dx2))*20 + q4]);
            }
        }
        float4 xc = *(const float4*)&xs[((py+3)*14 + (px1+3))*20 + q4];

        #define SPLIT4(arridx, v) { \
            unsigned short h0 = bf16_rne((v).x), h1 = bf16_rne((v).y); \
            unsigned short h2 = bf16_rne((v).z), h3 = bf16_rne((v).w); \
            unsigned short l0 = bf16_rne((v).x - bf16f(h0)); \
            unsigned short l1 = bf16_rne((v).y - bf16f(h1)); \
            unsigned short l2 = bf16_rne((v).z - bf16f(h2)); \
            unsigned short l3 = bf16_rne((v).w - bf16f(h3)); \
            *(ushort4*)&perc_hi[arridx] = make_ushort4(h0,h1,h2,h3); \
            *(ushort4*)&perc_lo[arridx] = make_ushort4(l0,l1,l2,l3); }

        const int prow = p * 136;
        SPLIT4(prow +       q4, xc);
        SPLIT4(prow + 16  + q4, y4[0]);
        SPLIT4(prow + 32  + q4, y4[1]);
        SPLIT4(prow + 48  + q4, y4[2]);
        SPLIT4(prow + 64  + q4, y4[3]);
        SPLIT4(prow + 80  + q4, y4[4]);
        SPLIT4(prow + 96  + q4, y4[5]);
        SPLIT4(prow + 112 + q4, m5);
        #undef SPLIT4

        if (q == 0) {
            float pre = -INFINITY;
            #pragma unroll
            for (int dy = -1; dy <= 1; dy++) {
                #pragma unroll
                for (int dx2 = -1; dx2 <= 1; dx2++) {
                    if ((unsigned)(gy+dy) < 256u && (unsigned)(gx+dx2) < 256u)
                        pre = fmaxf(pre, xs[((py+3+dy)*14 + (px1+3+dx2))*20 + 3]);
                }
            }
            prelife_out[(b << 16) + (gy << 8) + gx] = (pre > 0.1f) ? 1 : 0;
        }
    }
    __syncthreads();   // xs reads done; perc published. xs region -> w0.

    // ---- phase 2: GEMM1 + GEMM2 both MFMA ----
    const int lane = t & 63;
    const int wid  = t >> 6;        // m-tile (16 px)
    const int l15  = lane & 15;
    const int l4   = lane >> 4;
    const int aoff  = (wid*16 + l15)*136 + 8*l4;  // GEMM1 A base (+32*ks)
    const int boff0 = (l15)*136 + 8*l4;           // GEMM1 B, n-tile 0
    const int boff1 = (16 + l15)*136 + 8*l4;      // GEMM1 B, n-tile 1
    const int hwr   = (wid*16 + 4*l4)*36 + l15;   // hbuf write base (+r*36)
    const int hrd   = (wid*16 + l15)*36 + 8*l4;   // hbuf A-frag base
    const int w1off = l15*256 + 8*l4;             // W1T2 frag base (+jc*32)

    // hoist GEMM1 A-frags (loop-invariant)
    short8 ah0 = *(const short8*)&perc_hi[aoff +  0];
    short8 ah1 = *(const short8*)&perc_hi[aoff + 32];
    short8 ah2 = *(const short8*)&perc_hi[aoff + 64];
    short8 ah3 = *(const short8*)&perc_hi[aoff + 96];
    short8 al0 = *(const short8*)&perc_lo[aoff +  0];
    short8 al1 = *(const short8*)&perc_lo[aoff + 32];
    short8 al2 = *(const short8*)&perc_lo[aoff + 64];
    short8 al3 = *(const short8*)&perc_lo[aoff + 96];

    f32x4 dacc = {0.f, 0.f, 0.f, 0.f};   // dx accumulator (C: col=ch, row=px)

    // prologue: write chunk 0 -> A buf; prefetch chunk 1
    *(uint4*)&w0hA[swds]     = sh0;
    *(uint4*)&w0hA[swds + 8] = sh1;
    *(uint4*)&w0lA[swds]     = sl0;
    *(uint4*)&w0lA[swds + 8] = sl1;
    sh0 = *(const uint4*)&W0hiT[sgbase + 4096];
    sh1 = *(const uint4*)&W0hiT[sgbase + 4096 + 8];
    sl0 = *(const uint4*)&W0loT[sgbase + 4096];
    sl1 = *(const uint4*)&W0loT[sgbase + 4096 + 8];
    __syncthreads();   // w0(0) visible

    #pragma unroll 1
    for (int jc = 0; jc < 8; jc++) {
        const unsigned short* wrdh = (jc & 1) ? w0hB : w0hA;
        const unsigned short* wrdl = (jc & 1) ? w0lB : w0lA;
        unsigned short*       wwrh = (jc & 1) ? w0hA : w0hB;
        unsigned short*       wwrl = (jc & 1) ? w0lA : w0lB;

        f32x4 acc0 = {0.f, 0.f, 0.f, 0.f};
        f32x4 acc1 = {0.f, 0.f, 0.f, 0.f};

        #define KSTEP(accv, boff, AH, AL, ks) { \
            short8 bh = *(const short8*)&wrdh[(boff) + (ks)*32]; \
            short8 bl = *(const short8*)&wrdl[(boff) + (ks)*32]; \
            accv = __builtin_amdgcn_mfma_f32_16x16x32_bf16(AL, bh, accv, 0, 0, 0); \
            accv = __builtin_amdgcn_mfma_f32_16x16x32_bf16(AH, bl, accv, 0, 0, 0); \
            accv = __builtin_amdgcn_mfma_f32_16x16x32_bf16(AH, bh, accv, 0, 0, 0); }

        KSTEP(acc0, boff0, ah0, al0, 0)
        KSTEP(acc0, boff0, ah1, al1, 1)
        KSTEP(acc0, boff0, ah2, al2, 2)
        KSTEP(acc0, boff0, ah3, al3, 3)
        KSTEP(acc1, boff1, ah0, al0, 0)
        KSTEP(acc1, boff1, ah1, al1, 1)
        KSTEP(acc1, boff1, ah2, al2, 2)
        KSTEP(acc1, boff1, ah3, al3, 3)
        #undef KSTEP

        // bias+relu, split h -> hbuf (WAVE-LOCAL: no barrier needed)
        {
            float bias0 = b0[jc*32 + l15];
            float bias1 = b0[jc*32 + 16 + l15];
            #pragma unroll
            for (int r = 0; r < 4; r++) {
                float h0 = fmaxf(acc0[r] + bias0, 0.f);
                float h1 = fmaxf(acc1[r] + bias1, 0.f);
                unsigned short hh0 = bf16_rne(h0);
                unsigned short hl0 = bf16_rne(h0 - bf16f(hh0));
                unsigned short hh1 = bf16_rne(h1);
                unsigned short hl1 = bf16_rne(h1 - bf16f(hh1));
                hbuf_hi[hwr + r*36]      = hh0;
                hbuf_lo[hwr + r*36]      = hl0;
                hbuf_hi[hwr + r*36 + 16] = hh1;
                hbuf_lo[hwr + r*36 + 16] = hl1;
            }
        }

        // GEMM2: dacc += h(px x 32j) * W1T2(32j x 16ch), 3 MFMAs
        {
            short8 hhf = *(const short8*)&hbuf_hi[hrd];
            short8 hlf = *(const short8*)&hbuf_lo[hrd];
            short8 w1h = *(const short8*)&W1hiT2[w1off + jc*32];
            short8 w1l = *(const short8*)&W1loT2[w1off + jc*32];
            dacc = __builtin_amdgcn_mfma_f32_16x16x32_bf16(hlf, w1h, dacc, 0, 0, 0);
            dacc = __builtin_amdgcn_mfma_f32_16x16x32_bf16(hhf, w1l, dacc, 0, 0, 0);
            dacc = __builtin_amdgcn_mfma_f32_16x16x32_bf16(hhf, w1h, dacc, 0, 0, 0);
        }

        // stage chunk jc+1 into other buffer (holds consumed chunk jc-1)
        if (jc < 7) {
            *(uint4*)&wwrh[swds]     = sh0;
            *(uint4*)&wwrh[swds + 8] = sh1;
            *(uint4*)&wwrl[swds]     = sl0;
            *(uint4*)&wwrl[swds + 8] = sl1;
            if (jc < 6) {
                const int nb = sgbase + (jc + 2) * 4096;
                sh0 = *(const uint4*)&W0hiT[nb];
                sh1 = *(const uint4*)&W0hiT[nb + 8];
                sl0 = *(const uint4*)&W0loT[nb];
                sl1 = *(const uint4*)&W0loT[nb + 8];
            }
            __syncthreads();   // one barrier per chunk
        }
    }

    // ---- epilogue: lane = (ch=l15, px=16*wid+4*l4+r) ----
    const int pxb = wid*16 + 4*l4;
    #pragma unroll
    for (int r = 0; r < 4; r++) {
        const int px   = pxb + r;
        const int pix2 = (b << 16) + ((ty0 + (px >> 3)) << 8) + (tx0 + (px & 7));
        float fire = (stoch_s[pix2] > 0.5f) ? 1.f : 0.f;
        float xc = bf16f(perc_hi[px*136 + l15]) + bf16f(perc_lo[px*136 + l15]);
        xmid[((size_t)pix2 << 4) + l15] = fmaf(fire, dacc[r], xc);
    }
}

// Final life masking (after step 16): alpha read from xbuf channel 3.
__global__ void step_mask(float* __restrict__ xbuf,
                          const unsigned char* __restrict__ prelife,
                          const float* __restrict__ valid) {
    int pix = blockIdx.x * 256 + threadIdx.x;
    int b = pix >> 16;
    int y = (pix >> 8) & 255;
    int x = pix & 255;
    float m = -INFINITY;
    #pragma unroll
    for (int dy = -1; dy <= 1; dy++) {
        #pragma unroll
        for (int dxo = -1; dxo <= 1; dxo++) {
            int yy = y + dy, xx = x + dxo;
            if ((unsigned)yy < 256u && (unsigned)xx < 256u)
                m = fmaxf(m, xbuf[((size_t)((b << 16) + (yy << 8) + xx) << 4) + 3]);
        }
    }
    float s = (prelife[pix] != 0 && m > 0.1f) ? valid[pix] : 0.f;
    float4* xp = (float4*)&xbuf[(size_t)pix << 4];
    #pragma unroll
    for (int i = 0; i < 4; i++) {
        float4 v = xp[i];
        v.x *= s; v.y *= s; v.z *= s; v.w *= s;
        xp[i] = v;
    }
}

extern "C" void kernel_launch(void* const* d_in, const int* in_sizes, int n_in,
                              void* d_out, int out_size, void* d_ws, size_t ws_size,
                              hipStream_t stream) {
    const float* x0    = (const float*)d_in[0];
    const float* valid = (const float*)d_in[1];
    const float* stoch = (const float*)d_in[2];
    const float* W0    = (const float*)d_in[3];
    const float* b0    = (const float*)d_in[4];
    const float* W1    = (const float*)d_in[5];

    float* ws   = (float*)d_ws;
    float* xA   = ws;                                    // [0, 8388608)
    unsigned char* plA = (unsigned char*)(ws + 8388608); // 512KB
    unsigned char* plB = plA + 524288;                   // 512KB
    float* filt = ws + 8650752;                          // 320 fl
    unsigned short* W0hiT  = (unsigned short*)(ws + 8651072);  // 32768 us
    unsigned short* W0loT  = (unsigned short*)(ws + 8667456);  // 32768 us
    unsigned short* W1hiT2 = (unsigned short*)(ws + 8683840);  // 4096 us
    unsigned short* W1loT2 = (unsigned short*)(ws + 8685888);  // 4096 us
    float* out  = (float*)d_out;

    init_kernel<<<128, 256, 0, stream>>>(W0, W1, filt, W0hiT, W0loT,
                                         W1hiT2, W1loT2);

    const float* src = x0;
    for (int k = 1; k <= 16; k++) {
        float* dst = (k & 1) ? xA : out;          // step 16 lands in d_out
        unsigned char* wr = (k & 1) ? plB : plA;
        unsigned char* rd = (k & 1) ? plA : plB;
        step_main<<<dim3(32,32,8), 256, 0, stream>>>(
            src, dst, rd, wr, filt, W0hiT, W0loT, W1hiT2, W1loT2, b0,
            stoch + (size_t)(k-1)*NPIX, valid, (k > 1) ? 1 : 0);
        src = dst;
    }
    step_mask<<<NPIX/256, 256, 0, stream>>>(out, plA, valid);
}